// Round 4
// baseline (571.800 us; speedup 1.0000x reference)
//
#include <hip/hip_runtime.h>
#include <hip/hip_bf16.h>

#define NN 40000
#define NE 640000

typedef unsigned int u32;
typedef unsigned short u16;

// ---------------- static device scratch (direct symbol use; no d_ws) -------
__device__ float g_xf[(size_t)NN * 128];     // canonical f32 x       (20.5 MB)
__device__ float g_wf[41472];                // packed f32 weights/biases
__device__ int   g_flags[4];                 // [0]=floats-are-f32, [1]=edge stride (1 or 2)
__device__ int   g_cnt[NN];
__device__ int   g_cur[NN];
__device__ int   g_rowptr[NN + 1];
__device__ float g_dinv[NN];
__device__ int   g_csrc[NE];
__device__ float g_cw[NE];
__device__ float g_bufA[(size_t)NN * 128];   // 20.5 MB
__device__ float g_bufB[(size_t)NN * 128];   // 20.5 MB

// packed weight offsets: W1,b1,W2,b2,W3,b3,Wo,bo
#define OFF_W1 0
#define OFF_B1 16384
#define OFF_W2 16512
#define OFF_B2 32896
#define OFF_W3 33024
#define OFF_B3 41216
#define OFF_WO 41280
#define OFF_BO 41408

__device__ __forceinline__ float b2f(u16 v){ return __uint_as_float(((u32)v) << 16); }
__device__ __forceinline__ int clampi(int v, int lo, int hi){ return v < lo ? lo : (v > hi ? hi : v); }
__device__ __forceinline__ float* selbuf(int s){ return s == 0 ? g_xf : (s == 1 ? g_bufA : g_bufB); }

// ---- 0) runtime dtype detection (insurance; expected: f32 + int32) ----
__global__ __launch_bounds__(256) void k_detect(const u16* __restrict__ xf, const int* __restrict__ ei){
  __shared__ int c1, c2;
  if (threadIdx.x == 0){ c1 = 0; c2 = 0; }
  __syncthreads();
  int l1 = 0, l2 = 0;
  for (int i = threadIdx.x; i < 4096; i += 256){
    u16 v = xf[2 * i];                       // bf16 data: plausible exponent; f32 low-half: ~random
    int e = (v >> 7) & 0xff;
    if (v == 0 || (e >= 100 && e <= 140)) l1++;
    if (ei[2 * i + 1] == 0) l2++;            // int64 data: high int32 words all zero
  }
  atomicAdd(&c1, l1); atomicAdd(&c2, l2);
  __syncthreads();
  if (threadIdx.x == 0){
    g_flags[0] = (c1 < 2048) ? 1 : 0;        // 1 => float tensors are f32
    g_flags[1] = (c2 > 2048) ? 2 : 1;        // edge stride in int32 units
  }
}

// ---- 0b) canonicalize x to f32 ----
__global__ __launch_bounds__(256) void k_cvt_x(const void* __restrict__ xin){
  int i = blockIdx.x * 256 + threadIdx.x;
  if (i < NN * 128){
    g_xf[i] = g_flags[0] ? ((const float*)xin)[i] : b2f(((const u16*)xin)[i]);
  }
}

// ---- 0c) canonicalize weights/biases ----
__global__ __launch_bounds__(256) void k_cvt_w(const void* p0, const void* p1, const void* p2, const void* p3,
                                               const void* p4, const void* p5, const void* p6, const void* p7){
  const void* ps[8] = {p0,p1,p2,p3,p4,p5,p6,p7};
  const int sz[8]     = {16384,128,16384,128,8192,64,128,2};
  const int dstoff[8] = {OFF_W1,OFF_B1,OFF_W2,OFF_B2,OFF_W3,OFF_B3,OFF_WO,OFF_BO};
  const int blkoff[8] = {0,64,65,129,130,162,163,164};
  int b = (int)blockIdx.x, t = 0;
#pragma unroll
  for (int k = 0; k < 8; ++k) if (b >= blkoff[k]) t = k;
  int local = (b - blkoff[t]) * 256 + (int)threadIdx.x;
  if (local < sz[t]){
    g_wf[dstoff[t] + local] = g_flags[0] ? ((const float*)ps[t])[local]
                                         : b2f(((const u16*)ps[t])[local]);
  }
}

// ---- 0d) zero counters ----
__global__ __launch_bounds__(256) void k_zero(){
  int i = blockIdx.x * 256 + threadIdx.x;
  if (i < NN){ g_cnt[i] = 0; g_cur[i] = 0; }
}

// ---- 1) in-degree count over dst ----
__global__ __launch_bounds__(256) void k_count(const int* __restrict__ ei){
  int e = blockIdx.x * 256 + threadIdx.x;
  if (e < NE){
    int strd = g_flags[1];
    int d = clampi(ei[(size_t)(NE + e) * strd], 0, NN - 1);
    atomicAdd(&g_cnt[d], 1);
  }
}

// ---- 2) exclusive scan -> row_ptr; dinv = rsqrt(deg+1) ----
__global__ __launch_bounds__(1024) void k_scan(){
  __shared__ int sd[1024];
  __shared__ int carry;
  if (threadIdx.x == 0) carry = 0;
  __syncthreads();
  for (int base = 0; base < NN; base += 1024){
    int i = base + (int)threadIdx.x;
    int v = (i < NN) ? g_cnt[i] : 0;
    sd[threadIdx.x] = v;
    __syncthreads();
    for (int ofs = 1; ofs < 1024; ofs <<= 1){
      int t = (threadIdx.x >= (u32)ofs) ? sd[threadIdx.x - ofs] : 0;
      __syncthreads();
      sd[threadIdx.x] += t;
      __syncthreads();
    }
    int incl = sd[threadIdx.x];
    if (i < NN){
      g_rowptr[i] = carry + incl - v;
      g_dinv[i] = rsqrtf((float)(v + 1));
    }
    __syncthreads();
    if (threadIdx.x == 1023) carry += sd[1023];
    __syncthreads();
  }
  if (threadIdx.x == 0) g_rowptr[NN] = carry;
}

// ---- 3) scatter edges into CSR ----
__global__ __launch_bounds__(256) void k_fill(const int* __restrict__ ei){
  int e = blockIdx.x * 256 + threadIdx.x;
  if (e < NE){
    int strd = g_flags[1];
    int s = clampi(ei[(size_t)e * strd], 0, NN - 1);
    int d = clampi(ei[(size_t)(NE + e) * strd], 0, NN - 1);
    int pos = clampi(g_rowptr[d] + atomicAdd(&g_cur[d], 1), 0, NE - 1);
    g_csrc[pos] = s;
    g_cw[pos] = g_dinv[s];
  }
}

// ---- 4) GEMM: C[N x J] = A[N x 128] @ W[128 x J], f32; blockIdx.y = 64-col slice ----
template<int J>
__global__ __launch_bounds__(256) void k_gemm(int asel, int woff, int csel){
  const float* A = selbuf(asel);
  float* C = selbuf(csel);
  __shared__ float Wl[128 * 64];             // 32 KB: W[:, c0:c0+64]
  int c0 = (int)blockIdx.y * 64;
  for (int idx = threadIdx.x; idx < 128 * 64; idx += 256)
    Wl[idx] = g_wf[woff + (idx >> 6) * J + c0 + (idx & 63)];
  __syncthreads();
  int r = (int)blockIdx.x * 64 + ((int)threadIdx.x & 63);   // 625*64 == NN exactly
  int q = (int)threadIdx.x >> 6;             // 16-col quarter within the 64-col slice
  float acc[16];
#pragma unroll
  for (int j = 0; j < 16; ++j) acc[j] = 0.f;
  const float4* Arow = (const float4*)(A + (size_t)r * 128);
  for (int kc = 0; kc < 32; ++kc){
    float4 p = Arow[kc];
    float a[4] = {p.x, p.y, p.z, p.w};
#pragma unroll
    for (int t = 0; t < 4; ++t){
      const float* wrow = Wl + (kc * 4 + t) * 64 + q * 16;
#pragma unroll
      for (int j = 0; j < 16; ++j) acc[j] = fmaf(a[t], wrow[j], acc[j]);
    }
  }
  float4* Crow = (float4*)(C + (size_t)r * J + c0 + q * 16);
#pragma unroll
  for (int j = 0; j < 4; ++j)
    Crow[j] = make_float4(acc[4*j], acc[4*j+1], acc[4*j+2], acc[4*j+3]);
}

// ---- 5) CSR aggregation: out[i] = di*sum_e w_e*h[s_e] + di^2*h[i] + b ----
template<int J, bool RELU>
__global__ __launch_bounds__(256) void k_agg(int hsel, int boff, int osel, float* __restrict__ dout){
  const float* h = selbuf(hsel);
  float* out = selbuf(osel);
  int wid = (int)((blockIdx.x * 256 + threadIdx.x) >> 6);   // wave per node
  int lane = (int)threadIdx.x & 63;
  if (wid >= NN) return;
  float di = g_dinv[wid];
  int beg = g_rowptr[wid], end = g_rowptr[wid + 1];
  if (J == 128){
    int c = 2 * lane;
    float a0 = 0.f, a1 = 0.f;
    for (int e = beg; e < end; ++e){
      int s = clampi(g_csrc[e], 0, NN - 1);
      float w = g_cw[e];
      float2 p = *(const float2*)(h + (size_t)s * 128 + c);
      a0 = fmaf(w, p.x, a0);
      a1 = fmaf(w, p.y, a1);
    }
    float2 ps = *(const float2*)(h + (size_t)wid * 128 + c);
    float sd = di * di;
    a0 = a0 * di + sd * ps.x + g_wf[boff + c];
    a1 = a1 * di + sd * ps.y + g_wf[boff + c + 1];
    if (RELU){ a0 = fmaxf(a0, 0.f); a1 = fmaxf(a1, 0.f); }
    *(float2*)(out + (size_t)wid * 128 + c) = make_float2(a0, a1);
  } else {
    float a0 = 0.f;
    for (int e = beg; e < end; ++e){
      int s = clampi(g_csrc[e], 0, NN - 1);
      a0 = fmaf(g_cw[e], h[(size_t)s * 64 + lane], a0);
    }
    float sd = di * di;
    a0 = a0 * di + sd * h[(size_t)wid * 64 + lane] + g_wf[boff + lane];
    if (RELU) a0 = fmaxf(a0, 0.f);
    out[(size_t)wid * 64 + lane] = a0;       // keep in g_buf for k_out
    if (dout) dout[(size_t)wid * 64 + lane] = a0;   // output 1 (h embedding)
  }
}

// ---- 6) output head: out[N x 2] = h3[N x 64] @ Wout + bout (h3 in g_bufB) ----
__global__ __launch_bounds__(256) void k_out(float* __restrict__ out){
  __shared__ float Wl[128];
  __shared__ float bl[2];
  if (threadIdx.x < 128) Wl[threadIdx.x] = g_wf[OFF_WO + threadIdx.x];
  if (threadIdx.x < 2) bl[threadIdx.x] = g_wf[OFF_BO + threadIdx.x];
  __syncthreads();
  int i = blockIdx.x * 256 + threadIdx.x;
  if (i >= NN) return;
  const float4* hr = (const float4*)(g_bufB + (size_t)i * 64);
  float a0 = bl[0], a1 = bl[1];
#pragma unroll
  for (int c = 0; c < 16; ++c){
    float4 p = hr[c];
    float v[4] = {p.x, p.y, p.z, p.w};
#pragma unroll
    for (int t = 0; t < 4; ++t){
      int k = c * 4 + t;
      a0 = fmaf(v[t], Wl[k * 2 + 0], a0);
      a1 = fmaf(v[t], Wl[k * 2 + 1], a1);
    }
  }
  *(float2*)(out + (size_t)i * 2) = make_float2(a0, a1);
}

extern "C" void kernel_launch(void* const* d_in, const int* in_sizes, int n_in,
                              void* d_out, int out_size, void* d_ws, size_t ws_size,
                              hipStream_t stream){
  const int* ei = (const int*)d_in[1];
  float* out = (float*)d_out;                    // [N,2] then [N,64], f32
  float* h3  = out + (size_t)NN * 2;

  k_detect<<<1, 256, 0, stream>>>((const u16*)d_in[0], ei);
  k_cvt_x<<<(NN * 128 + 255) / 256, 256, 0, stream>>>(d_in[0]);
  k_cvt_w<<<165, 256, 0, stream>>>(d_in[2], d_in[3], d_in[4], d_in[5],
                                   d_in[6], d_in[7], d_in[8], d_in[9]);
  k_zero<<<(NN + 255) / 256, 256, 0, stream>>>();
  k_count<<<(NE + 255) / 256, 256, 0, stream>>>(ei);
  k_scan<<<1, 1024, 0, stream>>>();
  k_fill<<<(NE + 255) / 256, 256, 0, stream>>>(ei);

  k_gemm<128><<<dim3(625, 2), 256, 0, stream>>>(0, OFF_W1, 1);   // g_xf -> bufA
  k_agg<128, true><<<10000, 256, 0, stream>>>(1, OFF_B1, 2, (float*)nullptr); // bufA -> bufB
  k_gemm<128><<<dim3(625, 2), 256, 0, stream>>>(2, OFF_W2, 1);   // bufB -> bufA
  k_agg<128, true><<<10000, 256, 0, stream>>>(1, OFF_B2, 2, (float*)nullptr); // bufA -> bufB
  k_gemm<64><<<dim3(625, 1), 256, 0, stream>>>(2, OFF_W3, 1);    // bufB -> bufA
  k_agg<64, false><<<10000, 256, 0, stream>>>(1, OFF_B3, 2, h3); // bufA -> bufB + h3
  k_out<<<157, 256, 0, stream>>>(out);
}

// Round 5
// 457.767 us; speedup vs baseline: 1.2491x; 1.2491x over previous
//
#include <hip/hip_runtime.h>
#include <hip/hip_bf16.h>

#define NN 40000
#define NE 640000

typedef unsigned int u32;
typedef unsigned short u16;

// ---------------- static device scratch (direct symbol use; no d_ws) -------
__device__ float g_xf[(size_t)NN * 128];     // canonical f32 x       (20.5 MB)
__device__ float g_wf[41472];                // packed f32 weights/biases
__device__ int   g_flags[4];                 // [0]=floats-are-f32, [1]=edge stride (1 or 2)
__device__ int   g_cnt[NN];
__device__ int   g_cur[NN];
__device__ int   g_rowptr[NN + 1];
__device__ float g_dinv[NN];
__device__ int   g_csrc[NE];
__device__ float g_cw[NE];
__device__ int   g_bsum[64];
__device__ int   g_bpre[64];
__device__ float g_bufA[(size_t)NN * 128];   // 20.5 MB
__device__ float g_bufB[(size_t)NN * 128];   // 20.5 MB

// packed weight offsets: W1,b1,W2,b2,W3,b3,Wo,bo
#define OFF_W1 0
#define OFF_B1 16384
#define OFF_W2 16512
#define OFF_B2 32896
#define OFF_W3 33024
#define OFF_B3 41216
#define OFF_WO 41280
#define OFF_BO 41408

__device__ __forceinline__ float b2f(u16 v){ return __uint_as_float(((u32)v) << 16); }
__device__ __forceinline__ int clampi(int v, int lo, int hi){ return v < lo ? lo : (v > hi ? hi : v); }
__device__ __forceinline__ float* selbuf(int s){ return s == 0 ? g_xf : (s == 1 ? g_bufA : g_bufB); }

// ---- 0) runtime dtype detection (insurance; handles f32-or-bf16, i32-or-i64) ----
__global__ __launch_bounds__(256) void k_detect(const u16* __restrict__ xf, const int* __restrict__ ei){
  __shared__ int c1, c2;
  if (threadIdx.x == 0){ c1 = 0; c2 = 0; }
  __syncthreads();
  int l1 = 0, l2 = 0;
  for (int i = threadIdx.x; i < 4096; i += 256){
    u16 v = xf[2 * i];
    int e = (v >> 7) & 0xff;
    if (v == 0 || (e >= 100 && e <= 140)) l1++;
    if (ei[2 * i + 1] == 0) l2++;
  }
  atomicAdd(&c1, l1); atomicAdd(&c2, l2);
  __syncthreads();
  if (threadIdx.x == 0){
    g_flags[0] = (c1 < 2048) ? 1 : 0;        // 1 => float tensors are f32
    g_flags[1] = (c2 > 2048) ? 2 : 1;        // edge stride in int32 units
  }
}

// ---- 0b) canonicalize x to f32 ----
__global__ __launch_bounds__(256) void k_cvt_x(const void* __restrict__ xin){
  int i = blockIdx.x * 256 + threadIdx.x;
  if (i < NN * 128){
    g_xf[i] = g_flags[0] ? ((const float*)xin)[i] : b2f(((const u16*)xin)[i]);
  }
}

// ---- 0c) canonicalize weights/biases ----
__global__ __launch_bounds__(256) void k_cvt_w(const void* p0, const void* p1, const void* p2, const void* p3,
                                               const void* p4, const void* p5, const void* p6, const void* p7){
  const void* ps[8] = {p0,p1,p2,p3,p4,p5,p6,p7};
  const int sz[8]     = {16384,128,16384,128,8192,64,128,2};
  const int dstoff[8] = {OFF_W1,OFF_B1,OFF_W2,OFF_B2,OFF_W3,OFF_B3,OFF_WO,OFF_BO};
  const int blkoff[8] = {0,64,65,129,130,162,163,164};
  int b = (int)blockIdx.x, t = 0;
#pragma unroll
  for (int k = 0; k < 8; ++k) if (b >= blkoff[k]) t = k;
  int local = (b - blkoff[t]) * 256 + (int)threadIdx.x;
  if (local < sz[t]){
    g_wf[dstoff[t] + local] = g_flags[0] ? ((const float*)ps[t])[local]
                                         : b2f(((const u16*)ps[t])[local]);
  }
}

// ---- 0d) zero counters ----
__global__ __launch_bounds__(256) void k_zero(){
  int i = blockIdx.x * 256 + threadIdx.x;
  if (i < NN){ g_cnt[i] = 0; g_cur[i] = 0; }
}

// ---- 1) in-degree count over dst ----
__global__ __launch_bounds__(256) void k_count(const int* __restrict__ ei){
  int e = blockIdx.x * 256 + threadIdx.x;
  if (e < NE){
    int strd = g_flags[1];
    int d = clampi(ei[(size_t)(NE + e) * strd], 0, NN - 1);
    atomicAdd(&g_cnt[d], 1);
  }
}

// ---- 2a) block-level scan (40 blocks x 1024): local exclusive + block sums ----
__global__ __launch_bounds__(1024) void k_scan1(){
  int t = (int)threadIdx.x;
  int b = (int)blockIdx.x;
  int i = b * 1024 + t;
  int v = (i < NN) ? g_cnt[i] : 0;
  int lane = t & 63, wv = t >> 6;
  int x = v;
#pragma unroll
  for (int ofs = 1; ofs < 64; ofs <<= 1){
    int y = __shfl_up(x, ofs, 64);
    if (lane >= ofs) x += y;
  }
  __shared__ int wsum[16];
  if (lane == 63) wsum[wv] = x;
  __syncthreads();
  if (t < 16){
    int s = wsum[t];
#pragma unroll
    for (int ofs = 1; ofs < 16; ofs <<= 1){
      int y = __shfl_up(s, ofs, 64);
      if (t >= ofs) s += y;
    }
    wsum[t] = s;                         // inclusive wave-prefix
  }
  __syncthreads();
  int pre = (wv == 0) ? 0 : wsum[wv - 1];
  int incl = x + pre;
  if (i < NN){
    g_rowptr[i] = incl - v;              // block-local exclusive
    g_dinv[i] = rsqrtf((float)(v + 1));
  }
  if (t == 1023) g_bsum[b] = incl;       // block total
}

// ---- 2b) scan 40 block sums (1 wave) ----
__global__ __launch_bounds__(64) void k_scan2(){
  int t = (int)threadIdx.x;
  int v = (t < 40) ? g_bsum[t] : 0;
  int s = v;
#pragma unroll
  for (int ofs = 1; ofs < 64; ofs <<= 1){
    int y = __shfl_up(s, ofs, 64);
    if (t >= ofs) s += y;
  }
  if (t < 40) g_bpre[t] = s - v;         // exclusive block prefix
  if (t == 39) g_rowptr[NN] = s;         // grand total
}

// ---- 2c) add block offsets ----
__global__ __launch_bounds__(1024) void k_scan3(){
  int i = (int)blockIdx.x * 1024 + (int)threadIdx.x;
  if (i < NN) g_rowptr[i] += g_bpre[blockIdx.x];
}

// ---- 3) scatter edges into CSR ----
__global__ __launch_bounds__(256) void k_fill(const int* __restrict__ ei){
  int e = blockIdx.x * 256 + threadIdx.x;
  if (e < NE){
    int strd = g_flags[1];
    int s = clampi(ei[(size_t)e * strd], 0, NN - 1);
    int d = clampi(ei[(size_t)(NE + e) * strd], 0, NN - 1);
    int pos = clampi(g_rowptr[d] + atomicAdd(&g_cur[d], 1), 0, NE - 1);
    g_csrc[pos] = s;
    g_cw[pos] = g_dinv[s];
  }
}

// ---- 4) GEMM: C[N x J] = A[N x 128] @ W[128 x J]; 4 rows x 16 cols per thread ----
// block: 256 thr = 64 row-groups x 4 col-quarters; covers 256 rows x 64 cols (y-slice)
template<int J>
__global__ __launch_bounds__(256) void k_gemm(int asel, int woff, int csel){
  const float* A = selbuf(asel);
  float* C = selbuf(csel);
  __shared__ float Wl[128 * 64];             // 32 KB: W[:, c0:c0+64]
  int c0 = (int)blockIdx.y * 64;
  for (int idx = threadIdx.x; idx < 128 * 64; idx += 256)
    Wl[idx] = g_wf[woff + (idx >> 6) * J + c0 + (idx & 63)];
  __syncthreads();
  int q = (int)threadIdx.x >> 6;             // 16-col quarter
  int rid = (int)threadIdx.x & 63;
  int r0 = (int)blockIdx.x * 256 + rid * 4;
  float acc[4][16];
#pragma unroll
  for (int rr = 0; rr < 4; ++rr)
#pragma unroll
    for (int j = 0; j < 16; ++j) acc[rr][j] = 0.f;
  int rl[4];
#pragma unroll
  for (int rr = 0; rr < 4; ++rr) rl[rr] = min(r0 + rr, NN - 1);
  for (int kc = 0; kc < 32; ++kc){           // 4 k-values per iter
    float av[4][4];
#pragma unroll
    for (int rr = 0; rr < 4; ++rr){
      float4 p = *(const float4*)(A + (size_t)rl[rr] * 128 + kc * 4);
      av[rr][0] = p.x; av[rr][1] = p.y; av[rr][2] = p.z; av[rr][3] = p.w;
    }
    const float* wbase = Wl + kc * 4 * 64 + q * 16;
#pragma unroll
    for (int t = 0; t < 4; ++t){
      const float* wrow = wbase + t * 64;
#pragma unroll
      for (int j = 0; j < 16; ++j){
        float w = wrow[j];
#pragma unroll
        for (int rr = 0; rr < 4; ++rr)
          acc[rr][j] = fmaf(av[rr][t], w, acc[rr][j]);
      }
    }
  }
#pragma unroll
  for (int rr = 0; rr < 4; ++rr){
    int r = r0 + rr;
    if (r < NN){
      float4* Crow = (float4*)(C + (size_t)r * J + c0 + q * 16);
#pragma unroll
      for (int j = 0; j < 4; ++j)
        Crow[j] = make_float4(acc[rr][4*j], acc[rr][4*j+1], acc[rr][4*j+2], acc[rr][4*j+3]);
    }
  }
}

// ---- 5) CSR aggregation: 2 nodes per wave, float4 per lane (J=128) ----
template<int J, bool RELU>
__global__ __launch_bounds__(256) void k_agg(int hsel, int boff, int osel, float* __restrict__ dout){
  const float* h = selbuf(hsel);
  float* out = selbuf(osel);
  int wpair = (int)((blockIdx.x * 256 + threadIdx.x) >> 6);  // wave index
  int lane = (int)threadIdx.x & 63;
  int sub = lane >> 5, sl = lane & 31;       // half-wave = one node
  int wid = wpair * 2 + sub;
  if (wid >= NN) return;
  float di = g_dinv[wid];
  int beg = g_rowptr[wid], end = g_rowptr[wid + 1];
  if (J == 128){
    int c = sl * 4;                          // 32 lanes x 4 floats = 128 cols
    float a0 = 0.f, a1 = 0.f, a2 = 0.f, a3 = 0.f;
    for (int e = beg; e < end; ++e){
      int s = clampi(g_csrc[e], 0, NN - 1);
      float w = g_cw[e];
      float4 p = *(const float4*)(h + (size_t)s * 128 + c);
      a0 = fmaf(w, p.x, a0); a1 = fmaf(w, p.y, a1);
      a2 = fmaf(w, p.z, a2); a3 = fmaf(w, p.w, a3);
    }
    float4 ps = *(const float4*)(h + (size_t)wid * 128 + c);
    float sd = di * di;
    a0 = a0 * di + sd * ps.x + g_wf[boff + c];
    a1 = a1 * di + sd * ps.y + g_wf[boff + c + 1];
    a2 = a2 * di + sd * ps.z + g_wf[boff + c + 2];
    a3 = a3 * di + sd * ps.w + g_wf[boff + c + 3];
    if (RELU){
      a0 = fmaxf(a0, 0.f); a1 = fmaxf(a1, 0.f);
      a2 = fmaxf(a2, 0.f); a3 = fmaxf(a3, 0.f);
    }
    *(float4*)(out + (size_t)wid * 128 + c) = make_float4(a0, a1, a2, a3);
  } else {
    int c = sl * 2;                          // 32 lanes x 2 floats = 64 cols
    float a0 = 0.f, a1 = 0.f;
    for (int e = beg; e < end; ++e){
      int s = clampi(g_csrc[e], 0, NN - 1);
      float w = g_cw[e];
      float2 p = *(const float2*)(h + (size_t)s * 64 + c);
      a0 = fmaf(w, p.x, a0); a1 = fmaf(w, p.y, a1);
    }
    float2 ps = *(const float2*)(h + (size_t)wid * 64 + c);
    float sd = di * di;
    a0 = a0 * di + sd * ps.x + g_wf[boff + c];
    a1 = a1 * di + sd * ps.y + g_wf[boff + c + 1];
    if (RELU){ a0 = fmaxf(a0, 0.f); a1 = fmaxf(a1, 0.f); }
    *(float2*)(out + (size_t)wid * 64 + c) = make_float2(a0, a1);
    if (dout) *(float2*)(dout + (size_t)wid * 64 + c) = make_float2(a0, a1);
  }
}

// ---- 6) output head: out[N x 2] = h3[N x 64] @ Wout + bout (h3 in g_bufB) ----
__global__ __launch_bounds__(256) void k_out(float* __restrict__ out){
  __shared__ float Wl[128];
  __shared__ float bl[2];
  if (threadIdx.x < 128) Wl[threadIdx.x] = g_wf[OFF_WO + threadIdx.x];
  if (threadIdx.x < 2) bl[threadIdx.x] = g_wf[OFF_BO + threadIdx.x];
  __syncthreads();
  int i = blockIdx.x * 256 + threadIdx.x;
  if (i >= NN) return;
  const float4* hr = (const float4*)(g_bufB + (size_t)i * 64);
  float a0 = bl[0], a1 = bl[1];
#pragma unroll
  for (int c = 0; c < 16; ++c){
    float4 p = hr[c];
    float v[4] = {p.x, p.y, p.z, p.w};
#pragma unroll
    for (int t = 0; t < 4; ++t){
      int k = c * 4 + t;
      a0 = fmaf(v[t], Wl[k * 2 + 0], a0);
      a1 = fmaf(v[t], Wl[k * 2 + 1], a1);
    }
  }
  *(float2*)(out + (size_t)i * 2) = make_float2(a0, a1);
}

extern "C" void kernel_launch(void* const* d_in, const int* in_sizes, int n_in,
                              void* d_out, int out_size, void* d_ws, size_t ws_size,
                              hipStream_t stream){
  const int* ei = (const int*)d_in[1];
  float* out = (float*)d_out;                    // [N,2] then [N,64], f32
  float* h3  = out + (size_t)NN * 2;

  k_detect<<<1, 256, 0, stream>>>((const u16*)d_in[0], ei);
  k_cvt_x<<<(NN * 128 + 255) / 256, 256, 0, stream>>>(d_in[0]);
  k_cvt_w<<<165, 256, 0, stream>>>(d_in[2], d_in[3], d_in[4], d_in[5],
                                   d_in[6], d_in[7], d_in[8], d_in[9]);
  k_zero<<<(NN + 255) / 256, 256, 0, stream>>>();
  k_count<<<(NE + 255) / 256, 256, 0, stream>>>(ei);
  k_scan1<<<40, 1024, 0, stream>>>();
  k_scan2<<<1, 64, 0, stream>>>();
  k_scan3<<<40, 1024, 0, stream>>>();
  k_fill<<<(NE + 255) / 256, 256, 0, stream>>>(ei);

  k_gemm<128><<<dim3(157, 2), 256, 0, stream>>>(0, OFF_W1, 1);   // g_xf -> bufA
  k_agg<128, true><<<5000, 256, 0, stream>>>(1, OFF_B1, 2, (float*)nullptr);  // bufA -> bufB
  k_gemm<128><<<dim3(157, 2), 256, 0, stream>>>(2, OFF_W2, 1);   // bufB -> bufA
  k_agg<128, true><<<5000, 256, 0, stream>>>(1, OFF_B2, 2, (float*)nullptr);  // bufA -> bufB
  k_gemm<64><<<dim3(157, 1), 256, 0, stream>>>(2, OFF_W3, 1);    // bufB -> bufA
  k_agg<64, false><<<5000, 256, 0, stream>>>(1, OFF_B3, 2, h3);  // bufA -> bufB + h3
  k_out<<<157, 256, 0, stream>>>(out);
}

// Round 6
// 391.331 us; speedup vs baseline: 1.4612x; 1.1698x over previous
//
#include <hip/hip_runtime.h>
#include <hip/hip_bf16.h>

#define NN 40000
#define NE 640000

typedef unsigned int u32;
typedef unsigned short u16;

// ---------------- static device scratch (direct symbol use; no d_ws) -------
__device__ float g_xf[(size_t)NN * 128];     // canonical f32 x       (20.5 MB)
__device__ float g_wf[41472];                // packed f32 weights/biases
__device__ int   g_flags[4];                 // [0]=floats-are-f32, [1]=edge stride (1 or 2)
__device__ int   g_cnt[NN];
__device__ int   g_cur[NN];
__device__ int   g_rowptr[NN + 1];
__device__ float g_dinv[NN];
__device__ int   g_csrc[NE];
__device__ float g_cw[NE];
__device__ int   g_bsum[64];
__device__ int   g_bpre[64];
__device__ float g_bufA[(size_t)NN * 128];   // 20.5 MB
__device__ float g_bufB[(size_t)NN * 128];   // 20.5 MB

// packed weight offsets: W1,b1,W2,b2,W3,b3,Wo,bo
#define OFF_W1 0
#define OFF_B1 16384
#define OFF_W2 16512
#define OFF_B2 32896
#define OFF_W3 33024
#define OFF_B3 41216
#define OFF_WO 41280
#define OFF_BO 41408

__device__ __forceinline__ float b2f(u16 v){ return __uint_as_float(((u32)v) << 16); }
__device__ __forceinline__ int clampi(int v, int lo, int hi){ return v < lo ? lo : (v > hi ? hi : v); }
__device__ __forceinline__ float* selbuf(int s){ return s == 0 ? g_xf : (s == 1 ? g_bufA : g_bufB); }

// ---- 0) runtime dtype detection (insurance; handles f32-or-bf16, i32-or-i64) ----
__global__ __launch_bounds__(256) void k_detect(const u16* __restrict__ xf, const int* __restrict__ ei){
  __shared__ int c1, c2;
  if (threadIdx.x == 0){ c1 = 0; c2 = 0; }
  __syncthreads();
  int l1 = 0, l2 = 0;
  for (int i = threadIdx.x; i < 4096; i += 256){
    u16 v = xf[2 * i];
    int e = (v >> 7) & 0xff;
    if (v == 0 || (e >= 100 && e <= 140)) l1++;
    if (ei[2 * i + 1] == 0) l2++;
  }
  atomicAdd(&c1, l1); atomicAdd(&c2, l2);
  __syncthreads();
  if (threadIdx.x == 0){
    g_flags[0] = (c1 < 2048) ? 1 : 0;        // 1 => float tensors are f32
    g_flags[1] = (c2 > 2048) ? 2 : 1;        // edge stride in int32 units
  }
}

// ---- 0b) canonicalize x to f32 (vectorized) ----
__global__ __launch_bounds__(256) void k_cvt_x(const void* __restrict__ xin){
  int i = blockIdx.x * 256 + threadIdx.x;    // float4 index
  if (i < NN * 32){
    if (g_flags[0]){
      ((float4*)g_xf)[i] = ((const float4*)xin)[i];
    } else {
      const u16* p = (const u16*)xin + (size_t)i * 4;
      ((float4*)g_xf)[i] = make_float4(b2f(p[0]), b2f(p[1]), b2f(p[2]), b2f(p[3]));
    }
  }
}

// ---- 0c) canonicalize weights/biases ----
__global__ __launch_bounds__(256) void k_cvt_w(const void* p0, const void* p1, const void* p2, const void* p3,
                                               const void* p4, const void* p5, const void* p6, const void* p7){
  const void* ps[8] = {p0,p1,p2,p3,p4,p5,p6,p7};
  const int sz[8]     = {16384,128,16384,128,8192,64,128,2};
  const int dstoff[8] = {OFF_W1,OFF_B1,OFF_W2,OFF_B2,OFF_W3,OFF_B3,OFF_WO,OFF_BO};
  const int blkoff[8] = {0,64,65,129,130,162,163,164};
  int b = (int)blockIdx.x, t = 0;
#pragma unroll
  for (int k = 0; k < 8; ++k) if (b >= blkoff[k]) t = k;
  int local = (b - blkoff[t]) * 256 + (int)threadIdx.x;
  if (local < sz[t]){
    g_wf[dstoff[t] + local] = g_flags[0] ? ((const float*)ps[t])[local]
                                         : b2f(((const u16*)ps[t])[local]);
  }
}

// ---- 0d) zero counters ----
__global__ __launch_bounds__(256) void k_zero(){
  int i = blockIdx.x * 256 + threadIdx.x;
  if (i < NN){ g_cnt[i] = 0; g_cur[i] = 0; }
}

// ---- 1) in-degree count over dst ----
__global__ __launch_bounds__(256) void k_count(const int* __restrict__ ei){
  int e = blockIdx.x * 256 + threadIdx.x;
  if (e < NE){
    int strd = g_flags[1];
    int d = clampi(ei[(size_t)(NE + e) * strd], 0, NN - 1);
    atomicAdd(&g_cnt[d], 1);
  }
}

// ---- 2a) block-level scan (40 blocks x 1024) ----
__global__ __launch_bounds__(1024) void k_scan1(){
  int t = (int)threadIdx.x;
  int b = (int)blockIdx.x;
  int i = b * 1024 + t;
  int v = (i < NN) ? g_cnt[i] : 0;
  int lane = t & 63, wv = t >> 6;
  int x = v;
#pragma unroll
  for (int ofs = 1; ofs < 64; ofs <<= 1){
    int y = __shfl_up(x, ofs, 64);
    if (lane >= ofs) x += y;
  }
  __shared__ int wsum[16];
  if (lane == 63) wsum[wv] = x;
  __syncthreads();
  if (t < 16){
    int s = wsum[t];
#pragma unroll
    for (int ofs = 1; ofs < 16; ofs <<= 1){
      int y = __shfl_up(s, ofs, 64);
      if (t >= ofs) s += y;
    }
    wsum[t] = s;
  }
  __syncthreads();
  int pre = (wv == 0) ? 0 : wsum[wv - 1];
  int incl = x + pre;
  if (i < NN){
    g_rowptr[i] = incl - v;
    g_dinv[i] = rsqrtf((float)(v + 1));
  }
  if (t == 1023) g_bsum[b] = incl;
}

// ---- 2b) scan 40 block sums ----
__global__ __launch_bounds__(64) void k_scan2(){
  int t = (int)threadIdx.x;
  int v = (t < 40) ? g_bsum[t] : 0;
  int s = v;
#pragma unroll
  for (int ofs = 1; ofs < 64; ofs <<= 1){
    int y = __shfl_up(s, ofs, 64);
    if (t >= ofs) s += y;
  }
  if (t < 40) g_bpre[t] = s - v;
  if (t == 39) g_rowptr[NN] = s;
}

// ---- 2c) add block offsets ----
__global__ __launch_bounds__(1024) void k_scan3(){
  int i = (int)blockIdx.x * 1024 + (int)threadIdx.x;
  if (i < NN) g_rowptr[i] += g_bpre[blockIdx.x];
}

// ---- 3) scatter edges into CSR ----
__global__ __launch_bounds__(256) void k_fill(const int* __restrict__ ei){
  int e = blockIdx.x * 256 + threadIdx.x;
  if (e < NE){
    int strd = g_flags[1];
    int s = clampi(ei[(size_t)e * strd], 0, NN - 1);
    int d = clampi(ei[(size_t)(NE + e) * strd], 0, NN - 1);
    int pos = clampi(g_rowptr[d] + atomicAdd(&g_cur[d], 1), 0, NE - 1);
    g_csrc[pos] = s;
    g_cw[pos] = g_dinv[s];
  }
}

// ---- 4) Tiled GEMM: C[N x J] = A[N x 128] @ W[128 x J], f32, LDS-staged ----
// 625 blocks x 64 rows (exact). Thread: 4 rows x J/16 cols. K in two 64-chunks.
template<int J>
__global__ __launch_bounds__(256) void k_gemm(int asel, int woff, int csel){
  constexpr int CPT = J / 16;                // cols per thread: 8 (J=128) or 4 (J=64)
  const float* A = selbuf(asel);
  float* C = selbuf(csel);
  __shared__ float Asm[64][65];              // +1 pad: compute reads 2-way (free)
  __shared__ float Wsm[64][J];
  int tid = (int)threadIdx.x;
  int g = tid & 15;                          // row group: rows 4g..4g+3
  int c = tid >> 4;                          // col group: cols c*CPT..
  int row0 = (int)blockIdx.x * 64;
  float acc[4][CPT];
#pragma unroll
  for (int r = 0; r < 4; ++r)
#pragma unroll
    for (int j = 0; j < CPT; ++j) acc[r][j] = 0.f;

  for (int k0 = 0; k0 < 128; k0 += 64){
    // stage A tile: 64 rows x 64 k, coalesced 256B segments
    {
      int lane16 = tid & 15, rq = tid >> 4;
#pragma unroll
      for (int j = 0; j < 4; ++j){
        int r = rq + 16 * j;
        int kk = lane16 * 4;
        float4 p = *(const float4*)(A + (size_t)(row0 + r) * 128 + k0 + kk);
        Asm[r][kk + 0] = p.x; Asm[r][kk + 1] = p.y;
        Asm[r][kk + 2] = p.z; Asm[r][kk + 3] = p.w;
      }
    }
    // stage W chunk: 64 k x J cols, coalesced
    {
      constexpr int F4PR = J / 4;            // float4 per row
#pragma unroll
      for (int j = 0; j < (64 * F4PR) / 256; ++j){
        int f4 = tid + 256 * j;
        int kr = f4 / F4PR, c4 = (f4 % F4PR) * 4;
        float4 p = *(const float4*)(&g_wf[woff + (size_t)(k0 + kr) * J + c4]);
        *(float4*)(&Wsm[kr][c4]) = p;
      }
    }
    __syncthreads();
#pragma unroll 4
    for (int k = 0; k < 64; ++k){
      float av[4];
#pragma unroll
      for (int r = 0; r < 4; ++r) av[r] = Asm[4 * g + r][k];
      float wv[CPT];
#pragma unroll
      for (int j = 0; j < CPT; j += 4)
        *(float4*)(&wv[j]) = *(const float4*)(&Wsm[k][c * CPT + j]);
#pragma unroll
      for (int r = 0; r < 4; ++r)
#pragma unroll
        for (int j = 0; j < CPT; ++j)
          acc[r][j] = fmaf(av[r], wv[j], acc[r][j]);
    }
    __syncthreads();
  }
  // epilogue
#pragma unroll
  for (int r = 0; r < 4; ++r){
    float* Crow = C + (size_t)(row0 + 4 * g + r) * J + c * CPT;
#pragma unroll
    for (int j = 0; j < CPT; j += 4)
      *(float4*)(Crow + j) = make_float4(acc[r][j], acc[r][j+1], acc[r][j+2], acc[r][j+3]);
  }
}

// ---- 5) CSR aggregation: 2 nodes per wave, half-wave per node, 2x edge unroll ----
template<int J, bool RELU>
__global__ __launch_bounds__(256) void k_agg(int hsel, int boff, int osel, float* __restrict__ dout){
  const float* h = selbuf(hsel);
  float* out = selbuf(osel);
  int wpair = (int)((blockIdx.x * 256 + threadIdx.x) >> 6);
  int lane = (int)threadIdx.x & 63;
  int sub = lane >> 5, sl = lane & 31;
  int wid = wpair * 2 + sub;
  if (wid >= NN) return;
  float di = g_dinv[wid];
  int beg = g_rowptr[wid], end = g_rowptr[wid + 1];
  if (J == 128){
    int cc = sl * 4;
    float a0 = 0.f, a1 = 0.f, a2 = 0.f, a3 = 0.f;
    int e = beg;
    for (; e + 1 < end; e += 2){
      int s0 = clampi(g_csrc[e], 0, NN - 1);
      int s1 = clampi(g_csrc[e + 1], 0, NN - 1);
      float w0 = g_cw[e], w1 = g_cw[e + 1];
      float4 p0 = *(const float4*)(h + (size_t)s0 * 128 + cc);
      float4 p1 = *(const float4*)(h + (size_t)s1 * 128 + cc);
      a0 = fmaf(w0, p0.x, a0); a1 = fmaf(w0, p0.y, a1);
      a2 = fmaf(w0, p0.z, a2); a3 = fmaf(w0, p0.w, a3);
      a0 = fmaf(w1, p1.x, a0); a1 = fmaf(w1, p1.y, a1);
      a2 = fmaf(w1, p1.z, a2); a3 = fmaf(w1, p1.w, a3);
    }
    if (e < end){
      int s0 = clampi(g_csrc[e], 0, NN - 1);
      float w0 = g_cw[e];
      float4 p0 = *(const float4*)(h + (size_t)s0 * 128 + cc);
      a0 = fmaf(w0, p0.x, a0); a1 = fmaf(w0, p0.y, a1);
      a2 = fmaf(w0, p0.z, a2); a3 = fmaf(w0, p0.w, a3);
    }
    float4 ps = *(const float4*)(h + (size_t)wid * 128 + cc);
    float sd = di * di;
    a0 = a0 * di + sd * ps.x + g_wf[boff + cc];
    a1 = a1 * di + sd * ps.y + g_wf[boff + cc + 1];
    a2 = a2 * di + sd * ps.z + g_wf[boff + cc + 2];
    a3 = a3 * di + sd * ps.w + g_wf[boff + cc + 3];
    if (RELU){
      a0 = fmaxf(a0, 0.f); a1 = fmaxf(a1, 0.f);
      a2 = fmaxf(a2, 0.f); a3 = fmaxf(a3, 0.f);
    }
    *(float4*)(out + (size_t)wid * 128 + cc) = make_float4(a0, a1, a2, a3);
  } else {
    int cc = sl * 2;
    float a0 = 0.f, a1 = 0.f;
    int e = beg;
    for (; e + 1 < end; e += 2){
      int s0 = clampi(g_csrc[e], 0, NN - 1);
      int s1 = clampi(g_csrc[e + 1], 0, NN - 1);
      float w0 = g_cw[e], w1 = g_cw[e + 1];
      float2 p0 = *(const float2*)(h + (size_t)s0 * 64 + cc);
      float2 p1 = *(const float2*)(h + (size_t)s1 * 64 + cc);
      a0 = fmaf(w0, p0.x, a0); a1 = fmaf(w0, p0.y, a1);
      a0 = fmaf(w1, p1.x, a0); a1 = fmaf(w1, p1.y, a1);
    }
    if (e < end){
      int s0 = clampi(g_csrc[e], 0, NN - 1);
      float w0 = g_cw[e];
      float2 p0 = *(const float2*)(h + (size_t)s0 * 64 + cc);
      a0 = fmaf(w0, p0.x, a0); a1 = fmaf(w0, p0.y, a1);
    }
    float2 ps = *(const float2*)(h + (size_t)wid * 64 + cc);
    float sd = di * di;
    a0 = a0 * di + sd * ps.x + g_wf[boff + cc];
    a1 = a1 * di + sd * ps.y + g_wf[boff + cc + 1];
    if (RELU){ a0 = fmaxf(a0, 0.f); a1 = fmaxf(a1, 0.f); }
    *(float2*)(out + (size_t)wid * 64 + cc) = make_float2(a0, a1);
    if (dout) *(float2*)(dout + (size_t)wid * 64 + cc) = make_float2(a0, a1);
  }
}

// ---- 6) output head: out[N x 2] = h3[N x 64] @ Wout + bout (h3 in g_bufB) ----
__global__ __launch_bounds__(256) void k_out(float* __restrict__ out){
  __shared__ float Wl[128];
  __shared__ float bl[2];
  if (threadIdx.x < 128) Wl[threadIdx.x] = g_wf[OFF_WO + threadIdx.x];
  if (threadIdx.x < 2) bl[threadIdx.x] = g_wf[OFF_BO + threadIdx.x];
  __syncthreads();
  int i = blockIdx.x * 256 + threadIdx.x;
  if (i >= NN) return;
  const float4* hr = (const float4*)(g_bufB + (size_t)i * 64);
  float a0 = bl[0], a1 = bl[1];
#pragma unroll
  for (int c = 0; c < 16; ++c){
    float4 p = hr[c];
    float v[4] = {p.x, p.y, p.z, p.w};
#pragma unroll
    for (int t = 0; t < 4; ++t){
      int k = c * 4 + t;
      a0 = fmaf(v[t], Wl[k * 2 + 0], a0);
      a1 = fmaf(v[t], Wl[k * 2 + 1], a1);
    }
  }
  *(float2*)(out + (size_t)i * 2) = make_float2(a0, a1);
}

extern "C" void kernel_launch(void* const* d_in, const int* in_sizes, int n_in,
                              void* d_out, int out_size, void* d_ws, size_t ws_size,
                              hipStream_t stream){
  const int* ei = (const int*)d_in[1];
  float* out = (float*)d_out;                    // [N,2] then [N,64], f32
  float* h3  = out + (size_t)NN * 2;

  k_detect<<<1, 256, 0, stream>>>((const u16*)d_in[0], ei);
  k_cvt_x<<<5000, 256, 0, stream>>>(d_in[0]);
  k_cvt_w<<<165, 256, 0, stream>>>(d_in[2], d_in[3], d_in[4], d_in[5],
                                   d_in[6], d_in[7], d_in[8], d_in[9]);
  k_zero<<<(NN + 255) / 256, 256, 0, stream>>>();
  k_count<<<(NE + 255) / 256, 256, 0, stream>>>(ei);
  k_scan1<<<40, 1024, 0, stream>>>();
  k_scan2<<<1, 64, 0, stream>>>();
  k_scan3<<<40, 1024, 0, stream>>>();
  k_fill<<<(NE + 255) / 256, 256, 0, stream>>>(ei);

  k_gemm<128><<<625, 256, 0, stream>>>(0, OFF_W1, 1);            // g_xf -> bufA
  k_agg<128, true><<<5000, 256, 0, stream>>>(1, OFF_B1, 2, (float*)nullptr);  // bufA -> bufB
  k_gemm<128><<<625, 256, 0, stream>>>(2, OFF_W2, 1);            // bufB -> bufA
  k_agg<128, true><<<5000, 256, 0, stream>>>(1, OFF_B2, 2, (float*)nullptr);  // bufA -> bufB
  k_gemm<64><<<625, 256, 0, stream>>>(2, OFF_W3, 1);             // bufB -> bufA
  k_agg<64, false><<<5000, 256, 0, stream>>>(1, OFF_B3, 2, h3);  // bufA -> bufB + h3
  k_out<<<157, 256, 0, stream>>>(out);
}

// Round 7
// 378.187 us; speedup vs baseline: 1.5119x; 1.0348x over previous
//
#include <hip/hip_runtime.h>
#include <hip/hip_bf16.h>

#define NN 40000
#define NE 640000

typedef unsigned int u32;
typedef unsigned short u16;

// ---------------- static device scratch (direct symbol use; no d_ws) -------
__device__ float g_xf[(size_t)NN * 128];     // canonical f32 x (used only if input is bf16)
__device__ float g_wf[41472];                // packed f32 weights/biases
__device__ int   g_flags[4];                 // [0]=floats-are-f32, [1]=edge stride (1 or 2)
__device__ int   g_cnt[NN];
__device__ int   g_cur[NN];
__device__ int   g_rowptr[NN + 1];
__device__ float g_dinv[NN];
__device__ int   g_csrc[NE];
__device__ int   g_bsum[64];
__device__ int   g_bpre[64];
__device__ float g_bufA[(size_t)NN * 128];   // 20.5 MB
__device__ float g_bufB[(size_t)NN * 128];   // 20.5 MB

// packed weight offsets: W1,b1,W2,b2,W3,b3,Wo,bo
#define OFF_W1 0
#define OFF_B1 16384
#define OFF_W2 16512
#define OFF_B2 32896
#define OFF_W3 33024
#define OFF_B3 41216
#define OFF_WO 41280
#define OFF_BO 41408

__device__ __forceinline__ float b2f(u16 v){ return __uint_as_float(((u32)v) << 16); }
__device__ __forceinline__ int clampi(int v, int lo, int hi){ return v < lo ? lo : (v > hi ? hi : v); }

// ---- 0) runtime dtype detection ----
__global__ __launch_bounds__(256) void k_detect(const u16* __restrict__ xf, const int* __restrict__ ei){
  __shared__ int c1, c2;
  if (threadIdx.x == 0){ c1 = 0; c2 = 0; }
  __syncthreads();
  int l1 = 0, l2 = 0;
  for (int i = threadIdx.x; i < 4096; i += 256){
    u16 v = xf[2 * i];
    int e = (v >> 7) & 0xff;
    if (v == 0 || (e >= 100 && e <= 140)) l1++;
    if (ei[2 * i + 1] == 0) l2++;
  }
  atomicAdd(&c1, l1); atomicAdd(&c2, l2);
  __syncthreads();
  if (threadIdx.x == 0){
    g_flags[0] = (c1 < 2048) ? 1 : 0;        // 1 => float tensors are f32
    g_flags[1] = (c2 > 2048) ? 2 : 1;        // edge stride in int32 units
  }
}

// ---- 0b) canonicalize x to f32 — only needed when input is bf16 ----
__global__ __launch_bounds__(256) void k_cvt_x(const void* __restrict__ xin){
  if (g_flags[0]) return;                    // f32 input: GEMM reads it directly
  int i = blockIdx.x * 256 + threadIdx.x;    // float4 index
  if (i < NN * 32){
    const u16* p = (const u16*)xin + (size_t)i * 4;
    ((float4*)g_xf)[i] = make_float4(b2f(p[0]), b2f(p[1]), b2f(p[2]), b2f(p[3]));
  }
}

// ---- 0c) canonicalize weights/biases ----
__global__ __launch_bounds__(256) void k_cvt_w(const void* p0, const void* p1, const void* p2, const void* p3,
                                               const void* p4, const void* p5, const void* p6, const void* p7){
  const void* ps[8] = {p0,p1,p2,p3,p4,p5,p6,p7};
  const int sz[8]     = {16384,128,16384,128,8192,64,128,2};
  const int dstoff[8] = {OFF_W1,OFF_B1,OFF_W2,OFF_B2,OFF_W3,OFF_B3,OFF_WO,OFF_BO};
  const int blkoff[8] = {0,64,65,129,130,162,163,164};
  int b = (int)blockIdx.x, t = 0;
#pragma unroll
  for (int k = 0; k < 8; ++k) if (b >= blkoff[k]) t = k;
  int local = (b - blkoff[t]) * 256 + (int)threadIdx.x;
  if (local < sz[t]){
    g_wf[dstoff[t] + local] = g_flags[0] ? ((const float*)ps[t])[local]
                                         : b2f(((const u16*)ps[t])[local]);
  }
}

// ---- 0d) zero counters ----
__global__ __launch_bounds__(256) void k_zero(){
  int i = blockIdx.x * 256 + threadIdx.x;
  if (i < NN){ g_cnt[i] = 0; g_cur[i] = 0; }
}

// ---- 1) in-degree count over dst ----
__global__ __launch_bounds__(256) void k_count(const int* __restrict__ ei){
  int e = blockIdx.x * 256 + threadIdx.x;
  if (e < NE){
    int strd = g_flags[1];
    int d = clampi(ei[(size_t)(NE + e) * strd], 0, NN - 1);
    atomicAdd(&g_cnt[d], 1);
  }
}

// ---- 2a) block-level scan (40 blocks x 1024) ----
__global__ __launch_bounds__(1024) void k_scan1(){
  int t = (int)threadIdx.x;
  int b = (int)blockIdx.x;
  int i = b * 1024 + t;
  int v = (i < NN) ? g_cnt[i] : 0;
  int lane = t & 63, wv = t >> 6;
  int x = v;
#pragma unroll
  for (int ofs = 1; ofs < 64; ofs <<= 1){
    int y = __shfl_up(x, ofs, 64);
    if (lane >= ofs) x += y;
  }
  __shared__ int wsum[16];
  if (lane == 63) wsum[wv] = x;
  __syncthreads();
  if (t < 16){
    int s = wsum[t];
#pragma unroll
    for (int ofs = 1; ofs < 16; ofs <<= 1){
      int y = __shfl_up(s, ofs, 64);
      if (t >= ofs) s += y;
    }
    wsum[t] = s;
  }
  __syncthreads();
  int pre = (wv == 0) ? 0 : wsum[wv - 1];
  int incl = x + pre;
  if (i < NN){
    g_rowptr[i] = incl - v;
    g_dinv[i] = rsqrtf((float)(v + 1));
  }
  if (t == 1023) g_bsum[b] = incl;
}

// ---- 2b) scan 40 block sums ----
__global__ __launch_bounds__(64) void k_scan2(){
  int t = (int)threadIdx.x;
  int v = (t < 40) ? g_bsum[t] : 0;
  int s = v;
#pragma unroll
  for (int ofs = 1; ofs < 64; ofs <<= 1){
    int y = __shfl_up(s, ofs, 64);
    if (t >= ofs) s += y;
  }
  if (t < 40) g_bpre[t] = s - v;
  if (t == 39) g_rowptr[NN] = s;
}

// ---- 2c) add block offsets ----
__global__ __launch_bounds__(1024) void k_scan3(){
  int i = (int)blockIdx.x * 1024 + (int)threadIdx.x;
  if (i < NN) g_rowptr[i] += g_bpre[blockIdx.x];
}

// ---- 3) scatter edges into CSR: ONE 4B random write per edge ----
__global__ __launch_bounds__(256) void k_fill(const int* __restrict__ ei){
  int e = blockIdx.x * 256 + threadIdx.x;
  if (e < NE){
    int strd = g_flags[1];
    int s = clampi(ei[(size_t)e * strd], 0, NN - 1);
    int d = clampi(ei[(size_t)(NE + e) * strd], 0, NN - 1);
    int pos = clampi(g_rowptr[d] + atomicAdd(&g_cur[d], 1), 0, NE - 1);
    g_csrc[pos] = s;
  }
}

// ---- 4) Tiled GEMM: C[N x J] = A[N x 128] @ W[128 x J], f32, LDS-staged ----
template<int J>
__global__ __launch_bounds__(256) void k_gemm(int asel, int woff, int csel, const void* __restrict__ xraw){
  constexpr int CPT = J / 16;
  const float* A = (asel == 0) ? (g_flags[0] ? (const float*)xraw : g_xf)
                               : (asel == 1 ? g_bufA : g_bufB);
  float* C = (csel == 1) ? g_bufA : g_bufB;
  __shared__ float Asm[64][65];
  __shared__ float Wsm[64][J];
  int tid = (int)threadIdx.x;
  int g = tid & 15;
  int c = tid >> 4;
  int row0 = (int)blockIdx.x * 64;
  float acc[4][CPT];
#pragma unroll
  for (int r = 0; r < 4; ++r)
#pragma unroll
    for (int j = 0; j < CPT; ++j) acc[r][j] = 0.f;

  for (int k0 = 0; k0 < 128; k0 += 64){
    {
      int lane16 = tid & 15, rq = tid >> 4;
#pragma unroll
      for (int j = 0; j < 4; ++j){
        int r = rq + 16 * j;
        int kk = lane16 * 4;
        float4 p = *(const float4*)(A + (size_t)(row0 + r) * 128 + k0 + kk);
        Asm[r][kk + 0] = p.x; Asm[r][kk + 1] = p.y;
        Asm[r][kk + 2] = p.z; Asm[r][kk + 3] = p.w;
      }
    }
    {
      constexpr int F4PR = J / 4;
#pragma unroll
      for (int j = 0; j < (64 * F4PR) / 256; ++j){
        int f4 = tid + 256 * j;
        int kr = f4 / F4PR, c4 = (f4 % F4PR) * 4;
        float4 p = *(const float4*)(&g_wf[woff + (size_t)(k0 + kr) * J + c4]);
        *(float4*)(&Wsm[kr][c4]) = p;
      }
    }
    __syncthreads();
#pragma unroll 4
    for (int k = 0; k < 64; ++k){
      float av[4];
#pragma unroll
      for (int r = 0; r < 4; ++r) av[r] = Asm[4 * g + r][k];
      float wv[CPT];
#pragma unroll
      for (int j = 0; j < CPT; j += 4)
        *(float4*)(&wv[j]) = *(const float4*)(&Wsm[k][c * CPT + j]);
#pragma unroll
      for (int r = 0; r < 4; ++r)
#pragma unroll
        for (int j = 0; j < CPT; ++j)
          acc[r][j] = fmaf(av[r], wv[j], acc[r][j]);
    }
    __syncthreads();
  }
#pragma unroll
  for (int r = 0; r < 4; ++r){
    float* Crow = C + (size_t)(row0 + 4 * g + r) * J + c * CPT;
#pragma unroll
    for (int j = 0; j < CPT; j += 4)
      *(float4*)(Crow + j) = make_float4(acc[r][j], acc[r][j+1], acc[r][j+2], acc[r][j+3]);
  }
}

// ---- 5) CSR aggregation: 2 nodes/wave, half-wave/node; w = dinv[src] broadcast ----
template<int J, bool RELU>
__global__ __launch_bounds__(256) void k_agg(int hsel, int boff, int osel, float* __restrict__ dout){
  const float* h = (hsel == 1) ? g_bufA : g_bufB;
  float* out = (osel == 1) ? g_bufA : g_bufB;
  int wpair = (int)((blockIdx.x * 256 + threadIdx.x) >> 6);
  int lane = (int)threadIdx.x & 63;
  int sub = lane >> 5, sl = lane & 31;
  int wid = wpair * 2 + sub;
  if (wid >= NN) return;
  float di = g_dinv[wid];
  int beg = g_rowptr[wid], end = g_rowptr[wid + 1];
  if (J == 128){
    int cc = sl * 4;
    float a0 = 0.f, a1 = 0.f, a2 = 0.f, a3 = 0.f;
    int e = beg;
    for (; e + 1 < end; e += 2){
      int s0 = clampi(g_csrc[e], 0, NN - 1);
      int s1 = clampi(g_csrc[e + 1], 0, NN - 1);
      float w0 = g_dinv[s0], w1 = g_dinv[s1];
      float4 p0 = *(const float4*)(h + (size_t)s0 * 128 + cc);
      float4 p1 = *(const float4*)(h + (size_t)s1 * 128 + cc);
      a0 = fmaf(w0, p0.x, a0); a1 = fmaf(w0, p0.y, a1);
      a2 = fmaf(w0, p0.z, a2); a3 = fmaf(w0, p0.w, a3);
      a0 = fmaf(w1, p1.x, a0); a1 = fmaf(w1, p1.y, a1);
      a2 = fmaf(w1, p1.z, a2); a3 = fmaf(w1, p1.w, a3);
    }
    if (e < end){
      int s0 = clampi(g_csrc[e], 0, NN - 1);
      float w0 = g_dinv[s0];
      float4 p0 = *(const float4*)(h + (size_t)s0 * 128 + cc);
      a0 = fmaf(w0, p0.x, a0); a1 = fmaf(w0, p0.y, a1);
      a2 = fmaf(w0, p0.z, a2); a3 = fmaf(w0, p0.w, a3);
    }
    float4 ps = *(const float4*)(h + (size_t)wid * 128 + cc);
    float sd = di * di;
    a0 = a0 * di + sd * ps.x + g_wf[boff + cc];
    a1 = a1 * di + sd * ps.y + g_wf[boff + cc + 1];
    a2 = a2 * di + sd * ps.z + g_wf[boff + cc + 2];
    a3 = a3 * di + sd * ps.w + g_wf[boff + cc + 3];
    if (RELU){
      a0 = fmaxf(a0, 0.f); a1 = fmaxf(a1, 0.f);
      a2 = fmaxf(a2, 0.f); a3 = fmaxf(a3, 0.f);
    }
    *(float4*)(out + (size_t)wid * 128 + cc) = make_float4(a0, a1, a2, a3);
  } else {
    int cc = sl * 2;
    float a0 = 0.f, a1 = 0.f;
    int e = beg;
    for (; e + 1 < end; e += 2){
      int s0 = clampi(g_csrc[e], 0, NN - 1);
      int s1 = clampi(g_csrc[e + 1], 0, NN - 1);
      float w0 = g_dinv[s0], w1 = g_dinv[s1];
      float2 p0 = *(const float2*)(h + (size_t)s0 * 64 + cc);
      float2 p1 = *(const float2*)(h + (size_t)s1 * 64 + cc);
      a0 = fmaf(w0, p0.x, a0); a1 = fmaf(w0, p0.y, a1);
      a0 = fmaf(w1, p1.x, a0); a1 = fmaf(w1, p1.y, a1);
    }
    if (e < end){
      int s0 = clampi(g_csrc[e], 0, NN - 1);
      float w0 = g_dinv[s0];
      float2 p0 = *(const float2*)(h + (size_t)s0 * 64 + cc);
      a0 = fmaf(w0, p0.x, a0); a1 = fmaf(w0, p0.y, a1);
    }
    float2 ps = *(const float2*)(h + (size_t)wid * 64 + cc);
    float sd = di * di;
    a0 = a0 * di + sd * ps.x + g_wf[boff + cc];
    a1 = a1 * di + sd * ps.y + g_wf[boff + cc + 1];
    if (RELU){ a0 = fmaxf(a0, 0.f); a1 = fmaxf(a1, 0.f); }
    *(float2*)(dout + (size_t)wid * 64 + cc) = make_float2(a0, a1);   // h3 only
  }
}

// ---- 6) output head: out[N x 2] = h3[N x 64] @ Wout + bout ----
__global__ __launch_bounds__(256) void k_out(const float* __restrict__ h3, float* __restrict__ out){
  __shared__ float Wl[128];
  __shared__ float bl[2];
  if (threadIdx.x < 128) Wl[threadIdx.x] = g_wf[OFF_WO + threadIdx.x];
  if (threadIdx.x < 2) bl[threadIdx.x] = g_wf[OFF_BO + threadIdx.x];
  __syncthreads();
  int i = blockIdx.x * 256 + threadIdx.x;
  if (i >= NN) return;
  const float4* hr = (const float4*)(h3 + (size_t)i * 64);
  float a0 = bl[0], a1 = bl[1];
#pragma unroll
  for (int c = 0; c < 16; ++c){
    float4 p = hr[c];
    float v[4] = {p.x, p.y, p.z, p.w};
#pragma unroll
    for (int t = 0; t < 4; ++t){
      int k = c * 4 + t;
      a0 = fmaf(v[t], Wl[k * 2 + 0], a0);
      a1 = fmaf(v[t], Wl[k * 2 + 1], a1);
    }
  }
  *(float2*)(out + (size_t)i * 2) = make_float2(a0, a1);
}

extern "C" void kernel_launch(void* const* d_in, const int* in_sizes, int n_in,
                              void* d_out, int out_size, void* d_ws, size_t ws_size,
                              hipStream_t stream){
  const int* ei = (const int*)d_in[1];
  float* out = (float*)d_out;                    // [N,2] then [N,64], f32
  float* h3  = out + (size_t)NN * 2;

  k_detect<<<1, 256, 0, stream>>>((const u16*)d_in[0], ei);
  k_cvt_x<<<5000, 256, 0, stream>>>(d_in[0]);
  k_cvt_w<<<165, 256, 0, stream>>>(d_in[2], d_in[3], d_in[4], d_in[5],
                                   d_in[6], d_in[7], d_in[8], d_in[9]);
  k_zero<<<(NN + 255) / 256, 256, 0, stream>>>();
  k_count<<<(NE + 255) / 256, 256, 0, stream>>>(ei);
  k_scan1<<<40, 1024, 0, stream>>>();
  k_scan2<<<1, 64, 0, stream>>>();
  k_scan3<<<40, 1024, 0, stream>>>();
  k_fill<<<(NE + 255) / 256, 256, 0, stream>>>(ei);

  k_gemm<128><<<625, 256, 0, stream>>>(0, OFF_W1, 1, d_in[0]);   // x -> bufA
  k_agg<128, true><<<5000, 256, 0, stream>>>(1, OFF_B1, 2, (float*)nullptr);  // bufA -> bufB
  k_gemm<128><<<625, 256, 0, stream>>>(2, OFF_W2, 1, d_in[0]);   // bufB -> bufA
  k_agg<128, true><<<5000, 256, 0, stream>>>(1, OFF_B2, 2, (float*)nullptr);  // bufA -> bufB
  k_gemm<64><<<625, 256, 0, stream>>>(2, OFF_W3, 1, d_in[0]);    // bufB -> bufA
  k_agg<64, false><<<5000, 256, 0, stream>>>(1, OFF_B3, 2, h3);  // bufA -> h3 (d_out)
  k_out<<<157, 256, 0, stream>>>(h3, out);
}

// Round 9
// 322.735 us; speedup vs baseline: 1.7717x; 1.1718x over previous
//
#include <hip/hip_runtime.h>
#include <hip/hip_bf16.h>

#define NN 40000
#define NE 640000

typedef unsigned int u32;
typedef unsigned short u16;

// ---------------- static device scratch (direct symbol use; no d_ws) -------
__device__ float g_xf[(size_t)NN * 128];     // canonical f32 x (only if input is bf16)
__device__ float g_wf[41472];                // packed f32 weights/biases
__device__ int   g_flags[4];                 // [0]=floats-are-f32, [1]=edge stride (1 or 2)
__device__ int   g_cnt[NN];
__device__ int   g_cur[NN];
__device__ int   g_rowptr[NN + 1];
__device__ float g_dinv[NN];
__device__ int   g_csrc[NE];
__device__ int   g_bsum[64];
__device__ int   g_bpre[64];
__device__ u16   g_hb[(size_t)NN * 128];     // bf16 h (gemm output, gather operand) 10.2 MB
__device__ float g_bufF[(size_t)NN * 128];   // f32 agg output (next gemm's A) 20.5 MB

// packed weight offsets: W1,b1,W2,b2,W3,b3,Wo,bo
#define OFF_W1 0
#define OFF_B1 16384
#define OFF_W2 16512
#define OFF_B2 32896
#define OFF_W3 33024
#define OFF_B3 41216
#define OFF_WO 41280
#define OFF_BO 41408

__device__ __forceinline__ float b2f(u16 v){ return __uint_as_float(((u32)v) << 16); }
__device__ __forceinline__ float blo(u32 u){ return __uint_as_float(u << 16); }
__device__ __forceinline__ float bhi(u32 u){ return __uint_as_float(u & 0xffff0000u); }
__device__ __forceinline__ u32 f2bf(float f){
  u32 u = __float_as_uint(f);
  return (u + 0x7fffu + ((u >> 16) & 1u)) >> 16;   // RNE
}
__device__ __forceinline__ int clampi(int v, int lo, int hi){ return v < lo ? lo : (v > hi ? hi : v); }

// ---- 0) runtime dtype detection ----
__global__ __launch_bounds__(256) void k_detect(const u16* __restrict__ xf, const int* __restrict__ ei){
  __shared__ int c1, c2;
  if (threadIdx.x == 0){ c1 = 0; c2 = 0; }
  __syncthreads();
  int l1 = 0, l2 = 0;
  for (int i = threadIdx.x; i < 4096; i += 256){
    u16 v = xf[2 * i];
    int e = (v >> 7) & 0xff;
    if (v == 0 || (e >= 100 && e <= 140)) l1++;
    if (ei[2 * i + 1] == 0) l2++;
  }
  atomicAdd(&c1, l1); atomicAdd(&c2, l2);
  __syncthreads();
  if (threadIdx.x == 0){
    g_flags[0] = (c1 < 2048) ? 1 : 0;
    g_flags[1] = (c2 > 2048) ? 2 : 1;
  }
}

// ---- 0b) canonicalize x to f32 — only when input is bf16 ----
__global__ __launch_bounds__(256) void k_cvt_x(const void* __restrict__ xin){
  if (g_flags[0]) return;
  int i = blockIdx.x * 256 + threadIdx.x;
  if (i < NN * 32){
    const u16* p = (const u16*)xin + (size_t)i * 4;
    ((float4*)g_xf)[i] = make_float4(b2f(p[0]), b2f(p[1]), b2f(p[2]), b2f(p[3]));
  }
}

// ---- 0c) canonicalize weights/biases ----
__global__ __launch_bounds__(256) void k_cvt_w(const void* p0, const void* p1, const void* p2, const void* p3,
                                               const void* p4, const void* p5, const void* p6, const void* p7){
  const void* ps[8] = {p0,p1,p2,p3,p4,p5,p6,p7};
  const int sz[8]     = {16384,128,16384,128,8192,64,128,2};
  const int dstoff[8] = {OFF_W1,OFF_B1,OFF_W2,OFF_B2,OFF_W3,OFF_B3,OFF_WO,OFF_BO};
  const int blkoff[8] = {0,64,65,129,130,162,163,164};
  int b = (int)blockIdx.x, t = 0;
#pragma unroll
  for (int k = 0; k < 8; ++k) if (b >= blkoff[k]) t = k;
  int local = (b - blkoff[t]) * 256 + (int)threadIdx.x;
  if (local < sz[t]){
    g_wf[dstoff[t] + local] = g_flags[0] ? ((const float*)ps[t])[local]
                                         : b2f(((const u16*)ps[t])[local]);
  }
}

// ---- 0d) zero counters ----
__global__ __launch_bounds__(256) void k_zero(){
  int i = blockIdx.x * 256 + threadIdx.x;
  if (i < NN){ g_cnt[i] = 0; g_cur[i] = 0; }
}

// ---- 1) in-degree count over dst ----
__global__ __launch_bounds__(256) void k_count(const int* __restrict__ ei){
  int e = blockIdx.x * 256 + threadIdx.x;
  if (e < NE){
    int strd = g_flags[1];
    int d = clampi(ei[(size_t)(NE + e) * strd], 0, NN - 1);
    atomicAdd(&g_cnt[d], 1);
  }
}

// ---- 2a) block-level scan (40 blocks x 1024) ----
__global__ __launch_bounds__(1024) void k_scan1(){
  int t = (int)threadIdx.x;
  int b = (int)blockIdx.x;
  int i = b * 1024 + t;
  int v = (i < NN) ? g_cnt[i] : 0;
  int lane = t & 63, wv = t >> 6;
  int x = v;
#pragma unroll
  for (int ofs = 1; ofs < 64; ofs <<= 1){
    int y = __shfl_up(x, ofs, 64);
    if (lane >= ofs) x += y;
  }
  __shared__ int wsum[16];
  if (lane == 63) wsum[wv] = x;
  __syncthreads();
  if (t < 16){
    int s = wsum[t];
#pragma unroll
    for (int ofs = 1; ofs < 16; ofs <<= 1){
      int y = __shfl_up(s, ofs, 64);
      if (t >= ofs) s += y;
    }
    wsum[t] = s;
  }
  __syncthreads();
  int pre = (wv == 0) ? 0 : wsum[wv - 1];
  int incl = x + pre;
  if (i < NN){
    g_rowptr[i] = incl - v;
    g_dinv[i] = rsqrtf((float)(v + 1));
  }
  if (t == 1023) g_bsum[b] = incl;
}

// ---- 2b) scan 40 block sums ----
__global__ __launch_bounds__(64) void k_scan2(){
  int t = (int)threadIdx.x;
  int v = (t < 40) ? g_bsum[t] : 0;
  int s = v;
#pragma unroll
  for (int ofs = 1; ofs < 64; ofs <<= 1){
    int y = __shfl_up(s, ofs, 64);
    if (t >= ofs) s += y;
  }
  if (t < 40) g_bpre[t] = s - v;
  if (t == 39) g_rowptr[NN] = s;
}

// ---- 2c) add block offsets ----
__global__ __launch_bounds__(1024) void k_scan3(){
  int i = (int)blockIdx.x * 1024 + (int)threadIdx.x;
  if (i < NN) g_rowptr[i] += g_bpre[blockIdx.x];
}

// ---- 3) scatter edges into CSR: one 4B write per edge ----
__global__ __launch_bounds__(256) void k_fill(const int* __restrict__ ei){
  int e = blockIdx.x * 256 + threadIdx.x;
  if (e < NE){
    int strd = g_flags[1];
    int s = clampi(ei[(size_t)e * strd], 0, NN - 1);
    int d = clampi(ei[(size_t)(NE + e) * strd], 0, NN - 1);
    int pos = clampi(g_rowptr[d] + atomicAdd(&g_cur[d], 1), 0, NE - 1);
    g_csrc[pos] = s;
  }
}

// ---- 4) Tiled GEMM: C[N x J](bf16 in g_hb) = A[N x 128](f32) @ W[128 x J](f32) ----
template<int J>
__global__ __launch_bounds__(256) void k_gemm(int asel, int woff, const void* __restrict__ xraw){
  constexpr int CPT = J / 16;
  const float* A = (asel == 0) ? (g_flags[0] ? (const float*)xraw : g_xf) : g_bufF;
  __shared__ float Asm[64][65];
  __shared__ float Wsm[64][J];
  int tid = (int)threadIdx.x;
  int g = tid & 15;
  int c = tid >> 4;
  int row0 = (int)blockIdx.x * 64;
  float acc[4][CPT];
#pragma unroll
  for (int r = 0; r < 4; ++r)
#pragma unroll
    for (int j = 0; j < CPT; ++j) acc[r][j] = 0.f;

  for (int k0 = 0; k0 < 128; k0 += 64){
    {
      int lane16 = tid & 15, rq = tid >> 4;
#pragma unroll
      for (int j = 0; j < 4; ++j){
        int r = rq + 16 * j;
        int kk = lane16 * 4;
        float4 p = *(const float4*)(A + (size_t)(row0 + r) * 128 + k0 + kk);
        Asm[r][kk + 0] = p.x; Asm[r][kk + 1] = p.y;
        Asm[r][kk + 2] = p.z; Asm[r][kk + 3] = p.w;
      }
    }
    {
      constexpr int F4PR = J / 4;
#pragma unroll
      for (int j = 0; j < (64 * F4PR) / 256; ++j){
        int f4 = tid + 256 * j;
        int kr = f4 / F4PR, c4 = (f4 % F4PR) * 4;
        float4 p = *(const float4*)(&g_wf[woff + (size_t)(k0 + kr) * J + c4]);
        *(float4*)(&Wsm[kr][c4]) = p;
      }
    }
    __syncthreads();
#pragma unroll 4
    for (int k = 0; k < 64; ++k){
      float av[4];
#pragma unroll
      for (int r = 0; r < 4; ++r) av[r] = Asm[4 * g + r][k];
      float wv[CPT];
#pragma unroll
      for (int j = 0; j < CPT; j += 4)
        *(float4*)(&wv[j]) = *(const float4*)(&Wsm[k][c * CPT + j]);
#pragma unroll
      for (int r = 0; r < 4; ++r)
#pragma unroll
        for (int j = 0; j < CPT; ++j)
          acc[r][j] = fmaf(av[r], wv[j], acc[r][j]);
    }
    __syncthreads();
  }
  // epilogue: pack f32 -> bf16, vector store
#pragma unroll
  for (int r = 0; r < 4; ++r){
    u32 pk[CPT / 2];
#pragma unroll
    for (int j = 0; j < CPT; j += 2)
      pk[j >> 1] = f2bf(acc[r][j]) | (f2bf(acc[r][j + 1]) << 16);
    u16* Crow = g_hb + (size_t)(row0 + 4 * g + r) * J + c * CPT;
    if (CPT == 8) *(uint4*)Crow = *(const uint4*)pk;
    else          *(uint2*)Crow = *(const uint2*)pk;
  }
}

// ---- 5) CSR aggregation: bf16 gather, f32 accumulate; 2 nodes/wave ----
// dout == nullptr => write g_bufF (device symbol), else write dout (harness ptr)
template<int J, bool RELU>
__global__ __launch_bounds__(256) void k_agg(int boff, float* __restrict__ dout){
  float* fout = dout ? dout : g_bufF;
  int wpair = (int)((blockIdx.x * 256 + threadIdx.x) >> 6);
  int lane = (int)threadIdx.x & 63;
  int sub = lane >> 5, sl = lane & 31;
  int wid = wpair * 2 + sub;
  if (wid >= NN) return;
  float di = g_dinv[wid];
  int beg = g_rowptr[wid], end = g_rowptr[wid + 1];
  if (J == 128){
    int cc = sl * 4;                          // 4 cols per lane
    float a0 = 0.f, a1 = 0.f, a2 = 0.f, a3 = 0.f;
    int e = beg;
    for (; e + 3 < end; e += 4){
      int s0 = clampi(g_csrc[e], 0, NN - 1);
      int s1 = clampi(g_csrc[e + 1], 0, NN - 1);
      int s2 = clampi(g_csrc[e + 2], 0, NN - 1);
      int s3 = clampi(g_csrc[e + 3], 0, NN - 1);
      float w0 = g_dinv[s0], w1 = g_dinv[s1], w2 = g_dinv[s2], w3 = g_dinv[s3];
      uint2 p0 = *(const uint2*)(g_hb + (size_t)s0 * 128 + cc);
      uint2 p1 = *(const uint2*)(g_hb + (size_t)s1 * 128 + cc);
      uint2 p2 = *(const uint2*)(g_hb + (size_t)s2 * 128 + cc);
      uint2 p3 = *(const uint2*)(g_hb + (size_t)s3 * 128 + cc);
      a0 = fmaf(w0, blo(p0.x), a0); a1 = fmaf(w0, bhi(p0.x), a1);
      a2 = fmaf(w0, blo(p0.y), a2); a3 = fmaf(w0, bhi(p0.y), a3);
      a0 = fmaf(w1, blo(p1.x), a0); a1 = fmaf(w1, bhi(p1.x), a1);
      a2 = fmaf(w1, blo(p1.y), a2); a3 = fmaf(w1, bhi(p1.y), a3);
      a0 = fmaf(w2, blo(p2.x), a0); a1 = fmaf(w2, bhi(p2.x), a1);
      a2 = fmaf(w2, blo(p2.y), a2); a3 = fmaf(w2, bhi(p2.y), a3);
      a0 = fmaf(w3, blo(p3.x), a0); a1 = fmaf(w3, bhi(p3.x), a1);
      a2 = fmaf(w3, blo(p3.y), a2); a3 = fmaf(w3, bhi(p3.y), a3);
    }
    for (; e < end; ++e){
      int s0 = clampi(g_csrc[e], 0, NN - 1);
      float w0 = g_dinv[s0];
      uint2 p0 = *(const uint2*)(g_hb + (size_t)s0 * 128 + cc);
      a0 = fmaf(w0, blo(p0.x), a0); a1 = fmaf(w0, bhi(p0.x), a1);
      a2 = fmaf(w0, blo(p0.y), a2); a3 = fmaf(w0, bhi(p0.y), a3);
    }
    uint2 ps = *(const uint2*)(g_hb + (size_t)wid * 128 + cc);
    float sd = di * di;
    a0 = a0 * di + sd * blo(ps.x) + g_wf[boff + cc];
    a1 = a1 * di + sd * bhi(ps.x) + g_wf[boff + cc + 1];
    a2 = a2 * di + sd * blo(ps.y) + g_wf[boff + cc + 2];
    a3 = a3 * di + sd * bhi(ps.y) + g_wf[boff + cc + 3];
    if (RELU){
      a0 = fmaxf(a0, 0.f); a1 = fmaxf(a1, 0.f);
      a2 = fmaxf(a2, 0.f); a3 = fmaxf(a3, 0.f);
    }
    *(float4*)(fout + (size_t)wid * 128 + cc) = make_float4(a0, a1, a2, a3);
  } else {
    int cc = sl * 2;                          // 2 cols per lane
    float a0 = 0.f, a1 = 0.f;
    int e = beg;
    for (; e + 3 < end; e += 4){
      int s0 = clampi(g_csrc[e], 0, NN - 1);
      int s1 = clampi(g_csrc[e + 1], 0, NN - 1);
      int s2 = clampi(g_csrc[e + 2], 0, NN - 1);
      int s3 = clampi(g_csrc[e + 3], 0, NN - 1);
      float w0 = g_dinv[s0], w1 = g_dinv[s1], w2 = g_dinv[s2], w3 = g_dinv[s3];
      u32 p0 = *(const u32*)(g_hb + (size_t)s0 * 64 + cc);
      u32 p1 = *(const u32*)(g_hb + (size_t)s1 * 64 + cc);
      u32 p2 = *(const u32*)(g_hb + (size_t)s2 * 64 + cc);
      u32 p3 = *(const u32*)(g_hb + (size_t)s3 * 64 + cc);
      a0 = fmaf(w0, blo(p0), a0); a1 = fmaf(w0, bhi(p0), a1);
      a0 = fmaf(w1, blo(p1), a0); a1 = fmaf(w1, bhi(p1), a1);
      a0 = fmaf(w2, blo(p2), a0); a1 = fmaf(w2, bhi(p2), a1);
      a0 = fmaf(w3, blo(p3), a0); a1 = fmaf(w3, bhi(p3), a1);
    }
    for (; e < end; ++e){
      int s0 = clampi(g_csrc[e], 0, NN - 1);
      float w0 = g_dinv[s0];
      u32 p0 = *(const u32*)(g_hb + (size_t)s0 * 64 + cc);
      a0 = fmaf(w0, blo(p0), a0); a1 = fmaf(w0, bhi(p0), a1);
    }
    u32 ps = *(const u32*)(g_hb + (size_t)wid * 64 + cc);
    float sd = di * di;
    a0 = a0 * di + sd * blo(ps) + g_wf[boff + cc];
    a1 = a1 * di + sd * bhi(ps) + g_wf[boff + cc + 1];
    if (RELU){ a0 = fmaxf(a0, 0.f); a1 = fmaxf(a1, 0.f); }
    *(float2*)(fout + (size_t)wid * 64 + cc) = make_float2(a0, a1);
  }
}

// ---- 6) output head: out[N x 2] = h3[N x 64] @ Wout + bout ----
__global__ __launch_bounds__(256) void k_out(const float* __restrict__ h3, float* __restrict__ out){
  __shared__ float Wl[128];
  __shared__ float bl[2];
  if (threadIdx.x < 128) Wl[threadIdx.x] = g_wf[OFF_WO + threadIdx.x];
  if (threadIdx.x < 2) bl[threadIdx.x] = g_wf[OFF_BO + threadIdx.x];
  __syncthreads();
  int i = blockIdx.x * 256 + threadIdx.x;
  if (i >= NN) return;
  const float4* hr = (const float4*)(h3 + (size_t)i * 64);
  float a0 = bl[0], a1 = bl[1];
#pragma unroll
  for (int c = 0; c < 16; ++c){
    float4 p = hr[c];
    float v[4] = {p.x, p.y, p.z, p.w};
#pragma unroll
    for (int t = 0; t < 4; ++t){
      int k = c * 4 + t;
      a0 = fmaf(v[t], Wl[k * 2 + 0], a0);
      a1 = fmaf(v[t], Wl[k * 2 + 1], a1);
    }
  }
  *(float2*)(out + (size_t)i * 2) = make_float2(a0, a1);
}

extern "C" void kernel_launch(void* const* d_in, const int* in_sizes, int n_in,
                              void* d_out, int out_size, void* d_ws, size_t ws_size,
                              hipStream_t stream){
  const int* ei = (const int*)d_in[1];
  float* out = (float*)d_out;                    // [N,2] then [N,64], f32
  float* h3  = out + (size_t)NN * 2;

  k_detect<<<1, 256, 0, stream>>>((const u16*)d_in[0], ei);
  k_cvt_x<<<5000, 256, 0, stream>>>(d_in[0]);
  k_cvt_w<<<165, 256, 0, stream>>>(d_in[2], d_in[3], d_in[4], d_in[5],
                                   d_in[6], d_in[7], d_in[8], d_in[9]);
  k_zero<<<(NN + 255) / 256, 256, 0, stream>>>();
  k_count<<<(NE + 255) / 256, 256, 0, stream>>>(ei);
  k_scan1<<<40, 1024, 0, stream>>>();
  k_scan2<<<1, 64, 0, stream>>>();
  k_scan3<<<40, 1024, 0, stream>>>();
  k_fill<<<(NE + 255) / 256, 256, 0, stream>>>(ei);

  k_gemm<128><<<625, 256, 0, stream>>>(0, OFF_W1, d_in[0]);              // x -> g_hb (bf16)
  k_agg<128, true><<<5000, 256, 0, stream>>>(OFF_B1, (float*)nullptr);   // g_hb -> g_bufF
  k_gemm<128><<<625, 256, 0, stream>>>(1, OFF_W2, d_in[0]);              // g_bufF -> g_hb
  k_agg<128, true><<<5000, 256, 0, stream>>>(OFF_B2, (float*)nullptr);   // g_hb -> g_bufF
  k_gemm<64><<<625, 256, 0, stream>>>(1, OFF_W3, d_in[0]);               // g_bufF -> g_hb (N x 64)
  k_agg<64, false><<<5000, 256, 0, stream>>>(OFF_B3, h3);                // g_hb -> h3 (d_out)
  k_out<<<157, 256, 0, stream>>>(h3, out);
}

// Round 10
// 288.617 us; speedup vs baseline: 1.9812x; 1.1182x over previous
//
#include <hip/hip_runtime.h>
#include <hip/hip_bf16.h>

#define NN 40000
#define NE 640000

typedef unsigned int u32;
typedef unsigned short u16;
typedef __attribute__((ext_vector_type(8))) short bf16x8;
typedef __attribute__((ext_vector_type(4))) float f32x4;

// ---------------- static device scratch (direct symbol use; no d_ws) -------
__device__ float g_wf[41472];                // packed f32 weights/biases
__device__ u16   g_wp[40960];                // bf16 W1/W2/W3 in MFMA B-fragment layout
__device__ int   g_flags[4];                 // [0]=floats-are-f32, [1]=edge stride (1 or 2)
__device__ int   g_cnt[NN];
__device__ int   g_cur[NN];
__device__ int   g_rowptr[NN + 1];
__device__ float g_dinv[NN];
__device__ int   g_csrc[NE];
__device__ int   g_bsum[64];
__device__ int   g_bpre[64];
__device__ u16   g_ha[(size_t)NN * 128];     // bf16 A operand (x, then agg outputs)
__device__ u16   g_hb[(size_t)NN * 128];     // bf16 gemm output (gather operand)

// packed f32 weight offsets: W1,b1,W2,b2,W3,b3,Wo,bo
#define OFF_W1 0
#define OFF_B1 16384
#define OFF_W2 16512
#define OFF_B2 32896
#define OFF_W3 33024
#define OFF_B3 41216
#define OFF_WO 41280
#define OFF_BO 41408
// g_wp (bf16, MFMA-packed) offsets
#define WP_W1 0
#define WP_W2 16384
#define WP_W3 32768

__device__ __forceinline__ float b2f(u16 v){ return __uint_as_float(((u32)v) << 16); }
__device__ __forceinline__ float blo(u32 u){ return __uint_as_float(u << 16); }
__device__ __forceinline__ float bhi(u32 u){ return __uint_as_float(u & 0xffff0000u); }
__device__ __forceinline__ u32 f2bf(float f){
  u32 u = __float_as_uint(f);
  return (u + 0x7fffu + ((u >> 16) & 1u)) >> 16;   // RNE
}
__device__ __forceinline__ int clampi(int v, int lo, int hi){ return v < lo ? lo : (v > hi ? hi : v); }

// ---- 0) runtime dtype detection ----
__global__ __launch_bounds__(256) void k_detect(const u16* __restrict__ xf, const int* __restrict__ ei){
  __shared__ int c1, c2;
  if (threadIdx.x == 0){ c1 = 0; c2 = 0; }
  __syncthreads();
  int l1 = 0, l2 = 0;
  for (int i = threadIdx.x; i < 4096; i += 256){
    u16 v = xf[2 * i];
    int e = (v >> 7) & 0xff;
    if (v == 0 || (e >= 100 && e <= 140)) l1++;
    if (ei[2 * i + 1] == 0) l2++;
  }
  atomicAdd(&c1, l1); atomicAdd(&c2, l2);
  __syncthreads();
  if (threadIdx.x == 0){
    g_flags[0] = (c1 < 2048) ? 1 : 0;
    g_flags[1] = (c2 > 2048) ? 2 : 1;
  }
}

// ---- 0b) x -> bf16 g_ha (8 elems/thread) ----
__global__ __launch_bounds__(256) void k_cvt_x(const void* __restrict__ xin){
  int i = blockIdx.x * 256 + threadIdx.x;        // 8-element group
  if (i >= NN * 16) return;
  if (g_flags[0]){
    const float4* p = (const float4*)xin + (size_t)i * 2;
    float4 a = p[0], b = p[1];
    uint4 o;
    o.x = f2bf(a.x) | (f2bf(a.y) << 16);
    o.y = f2bf(a.z) | (f2bf(a.w) << 16);
    o.z = f2bf(b.x) | (f2bf(b.y) << 16);
    o.w = f2bf(b.z) | (f2bf(b.w) << 16);
    ((uint4*)g_ha)[i] = o;
  } else {
    ((uint4*)g_ha)[i] = ((const uint4*)xin)[i];
  }
}

// ---- 0c) canonicalize weights/biases to f32 g_wf ----
__global__ __launch_bounds__(256) void k_cvt_w(const void* p0, const void* p1, const void* p2, const void* p3,
                                               const void* p4, const void* p5, const void* p6, const void* p7){
  const void* ps[8] = {p0,p1,p2,p3,p4,p5,p6,p7};
  const int sz[8]     = {16384,128,16384,128,8192,64,128,2};
  const int dstoff[8] = {OFF_W1,OFF_B1,OFF_W2,OFF_B2,OFF_W3,OFF_B3,OFF_WO,OFF_BO};
  const int blkoff[8] = {0,64,65,129,130,162,163,164};
  int b = (int)blockIdx.x, t = 0;
#pragma unroll
  for (int k = 0; k < 8; ++k) if (b >= blkoff[k]) t = k;
  int local = (b - blkoff[t]) * 256 + (int)threadIdx.x;
  if (local < sz[t]){
    g_wf[dstoff[t] + local] = g_flags[0] ? ((const float*)ps[t])[local]
                                         : b2f(((const u16*)ps[t])[local]);
  }
}

// ---- 0c2) pack W1/W2/W3 into MFMA B-fragment layout (bf16) ----
// dst[(kb*(J/16)+nb)*512 + lane*8 + j] = W[kb*32 + (lane>>4)*8 + j][nb*16 + (lane&15)]
__global__ __launch_bounds__(256) void k_packw(){
  int tid = (int)blockIdx.x * 256 + (int)threadIdx.x;   // 0..40959
  if (tid >= 40960) return;
  int J, srcoff, dstbase, local;
  if (tid < 16384){ J = 128; srcoff = OFF_W1; dstbase = WP_W1; local = tid; }
  else if (tid < 32768){ J = 128; srcoff = OFF_W2; dstbase = WP_W2; local = tid - 16384; }
  else { J = 64; srcoff = OFF_W3; dstbase = WP_W3; local = tid - 32768; }
  int chunk = local >> 9, within = local & 511;
  int nbw = J / 16;
  int kb = chunk / nbw, nb = chunk % nbw;
  int lane = within >> 3, j = within & 7;
  int q = lane >> 4, n = lane & 15;
  int k = kb * 32 + q * 8 + j;
  int col = nb * 16 + n;
  g_wp[dstbase + local] = (u16)f2bf(g_wf[srcoff + (size_t)k * J + col]);
}

// ---- 0d) zero counters ----
__global__ __launch_bounds__(256) void k_zero(){
  int i = blockIdx.x * 256 + threadIdx.x;
  if (i < NN){ g_cnt[i] = 0; g_cur[i] = 0; }
}

// ---- 1) in-degree count over dst ----
__global__ __launch_bounds__(256) void k_count(const int* __restrict__ ei){
  int e = blockIdx.x * 256 + threadIdx.x;
  if (e < NE){
    int strd = g_flags[1];
    int d = clampi(ei[(size_t)(NE + e) * strd], 0, NN - 1);
    atomicAdd(&g_cnt[d], 1);
  }
}

// ---- 2a) block-level scan (40 blocks x 1024) ----
__global__ __launch_bounds__(1024) void k_scan1(){
  int t = (int)threadIdx.x;
  int b = (int)blockIdx.x;
  int i = b * 1024 + t;
  int v = (i < NN) ? g_cnt[i] : 0;
  int lane = t & 63, wv = t >> 6;
  int x = v;
#pragma unroll
  for (int ofs = 1; ofs < 64; ofs <<= 1){
    int y = __shfl_up(x, ofs, 64);
    if (lane >= ofs) x += y;
  }
  __shared__ int wsum[16];
  if (lane == 63) wsum[wv] = x;
  __syncthreads();
  if (t < 16){
    int s = wsum[t];
#pragma unroll
    for (int ofs = 1; ofs < 16; ofs <<= 1){
      int y = __shfl_up(s, ofs, 64);
      if (t >= ofs) s += y;
    }
    wsum[t] = s;
  }
  __syncthreads();
  int pre = (wv == 0) ? 0 : wsum[wv - 1];
  int incl = x + pre;
  if (i < NN){
    g_rowptr[i] = incl - v;
    g_dinv[i] = rsqrtf((float)(v + 1));
  }
  if (t == 1023) g_bsum[b] = incl;
}

// ---- 2b) scan 40 block sums ----
__global__ __launch_bounds__(64) void k_scan2(){
  int t = (int)threadIdx.x;
  int v = (t < 40) ? g_bsum[t] : 0;
  int s = v;
#pragma unroll
  for (int ofs = 1; ofs < 64; ofs <<= 1){
    int y = __shfl_up(s, ofs, 64);
    if (t >= ofs) s += y;
  }
  if (t < 40) g_bpre[t] = s - v;
  if (t == 39) g_rowptr[NN] = s;
}

// ---- 2c) add block offsets ----
__global__ __launch_bounds__(1024) void k_scan3(){
  int i = (int)blockIdx.x * 1024 + (int)threadIdx.x;
  if (i < NN) g_rowptr[i] += g_bpre[blockIdx.x];
}

// ---- 3) scatter edges into CSR ----
__global__ __launch_bounds__(256) void k_fill(const int* __restrict__ ei){
  int e = blockIdx.x * 256 + threadIdx.x;
  if (e < NE){
    int strd = g_flags[1];
    int s = clampi(ei[(size_t)e * strd], 0, NN - 1);
    int d = clampi(ei[(size_t)(NE + e) * strd], 0, NN - 1);
    int pos = clampi(g_rowptr[d] + atomicAdd(&g_cur[d], 1), 0, NE - 1);
    g_csrc[pos] = s;
  }
}

// ---- 4) MFMA GEMM: g_hb[N x J](bf16) = g_ha[N x 128](bf16) @ W(packed bf16) ----
// 625 blocks x 4 waves; wave = 16 rows x J cols; K=128 in 4 chunks of 32.
// A frag: A[m=lane&15][k=quad*8+j]; B frag from g_wp (pre-packed); C: col=lane&15,row=quad*4+reg.
template<int J>
__global__ __launch_bounds__(256) void k_gemm(int wpoff){
  constexpr int NB = J / 16;
  int tid = (int)threadIdx.x;
  int wave = tid >> 6, lane = tid & 63;
  int q = lane >> 4, n = lane & 15;
  int m0 = (int)blockIdx.x * 64 + wave * 16;
  f32x4 acc[NB];
#pragma unroll
  for (int nb = 0; nb < NB; ++nb) acc[nb] = (f32x4){0.f, 0.f, 0.f, 0.f};
  const u16* arow = g_ha + (size_t)(m0 + n) * 128 + q * 8;
#pragma unroll
  for (int kb = 0; kb < 4; ++kb){
    bf16x8 a = *(const bf16x8*)(arow + kb * 32);
    const u16* wbase = g_wp + wpoff + (kb * NB) * 512 + lane * 8;
#pragma unroll
    for (int nb = 0; nb < NB; ++nb){
      bf16x8 w = *(const bf16x8*)(wbase + nb * 512);
      acc[nb] = __builtin_amdgcn_mfma_f32_16x16x32_bf16(a, w, acc[nb], 0, 0, 0);
    }
  }
  // store: row = m0 + q*4 + r, col = nb*16 + n
  u16* crow = g_hb + (size_t)(m0 + q * 4) * J + n;
#pragma unroll
  for (int r = 0; r < 4; ++r){
#pragma unroll
    for (int nb = 0; nb < NB; ++nb)
      crow[(size_t)r * J + nb * 16] = (u16)f2bf(acc[nb][r]);
  }
}

// ---- 5) CSR aggregation: bf16 gather, f32 acc; layer 1/2 -> bf16 g_ha, layer 3 -> f32 dout ----
template<int J, bool RELU>
__global__ __launch_bounds__(256) void k_agg(int boff, float* __restrict__ dout){
  int wpair = (int)((blockIdx.x * 256 + threadIdx.x) >> 6);
  int lane = (int)threadIdx.x & 63;
  int sub = lane >> 5, sl = lane & 31;
  int wid = wpair * 2 + sub;
  if (wid >= NN) return;
  float di = g_dinv[wid];
  int beg = g_rowptr[wid], end = g_rowptr[wid + 1];
  if (J == 128){
    int cc = sl * 4;                          // 4 cols per lane
    float a0 = 0.f, a1 = 0.f, a2 = 0.f, a3 = 0.f;
    int e = beg;
    for (; e + 3 < end; e += 4){
      int s0 = clampi(g_csrc[e], 0, NN - 1);
      int s1 = clampi(g_csrc[e + 1], 0, NN - 1);
      int s2 = clampi(g_csrc[e + 2], 0, NN - 1);
      int s3 = clampi(g_csrc[e + 3], 0, NN - 1);
      float w0 = g_dinv[s0], w1 = g_dinv[s1], w2 = g_dinv[s2], w3 = g_dinv[s3];
      uint2 p0 = *(const uint2*)(g_hb + (size_t)s0 * 128 + cc);
      uint2 p1 = *(const uint2*)(g_hb + (size_t)s1 * 128 + cc);
      uint2 p2 = *(const uint2*)(g_hb + (size_t)s2 * 128 + cc);
      uint2 p3 = *(const uint2*)(g_hb + (size_t)s3 * 128 + cc);
      a0 = fmaf(w0, blo(p0.x), a0); a1 = fmaf(w0, bhi(p0.x), a1);
      a2 = fmaf(w0, blo(p0.y), a2); a3 = fmaf(w0, bhi(p0.y), a3);
      a0 = fmaf(w1, blo(p1.x), a0); a1 = fmaf(w1, bhi(p1.x), a1);
      a2 = fmaf(w1, blo(p1.y), a2); a3 = fmaf(w1, bhi(p1.y), a3);
      a0 = fmaf(w2, blo(p2.x), a0); a1 = fmaf(w2, bhi(p2.x), a1);
      a2 = fmaf(w2, blo(p2.y), a2); a3 = fmaf(w2, bhi(p2.y), a3);
      a0 = fmaf(w3, blo(p3.x), a0); a1 = fmaf(w3, bhi(p3.x), a1);
      a2 = fmaf(w3, blo(p3.y), a2); a3 = fmaf(w3, bhi(p3.y), a3);
    }
    for (; e < end; ++e){
      int s0 = clampi(g_csrc[e], 0, NN - 1);
      float w0 = g_dinv[s0];
      uint2 p0 = *(const uint2*)(g_hb + (size_t)s0 * 128 + cc);
      a0 = fmaf(w0, blo(p0.x), a0); a1 = fmaf(w0, bhi(p0.x), a1);
      a2 = fmaf(w0, blo(p0.y), a2); a3 = fmaf(w0, bhi(p0.y), a3);
    }
    uint2 ps = *(const uint2*)(g_hb + (size_t)wid * 128 + cc);
    float sd = di * di;
    a0 = a0 * di + sd * blo(ps.x) + g_wf[boff + cc];
    a1 = a1 * di + sd * bhi(ps.x) + g_wf[boff + cc + 1];
    a2 = a2 * di + sd * blo(ps.y) + g_wf[boff + cc + 2];
    a3 = a3 * di + sd * bhi(ps.y) + g_wf[boff + cc + 3];
    if (RELU){
      a0 = fmaxf(a0, 0.f); a1 = fmaxf(a1, 0.f);
      a2 = fmaxf(a2, 0.f); a3 = fmaxf(a3, 0.f);
    }
    uint2 o;
    o.x = f2bf(a0) | (f2bf(a1) << 16);
    o.y = f2bf(a2) | (f2bf(a3) << 16);
    *(uint2*)(g_ha + (size_t)wid * 128 + cc) = o;   // bf16 A for next gemm
  } else {
    int cc = sl * 2;
    float a0 = 0.f, a1 = 0.f;
    int e = beg;
    for (; e + 3 < end; e += 4){
      int s0 = clampi(g_csrc[e], 0, NN - 1);
      int s1 = clampi(g_csrc[e + 1], 0, NN - 1);
      int s2 = clampi(g_csrc[e + 2], 0, NN - 1);
      int s3 = clampi(g_csrc[e + 3], 0, NN - 1);
      float w0 = g_dinv[s0], w1 = g_dinv[s1], w2 = g_dinv[s2], w3 = g_dinv[s3];
      u32 p0 = *(const u32*)(g_hb + (size_t)s0 * 64 + cc);
      u32 p1 = *(const u32*)(g_hb + (size_t)s1 * 64 + cc);
      u32 p2 = *(const u32*)(g_hb + (size_t)s2 * 64 + cc);
      u32 p3 = *(const u32*)(g_hb + (size_t)s3 * 64 + cc);
      a0 = fmaf(w0, blo(p0), a0); a1 = fmaf(w0, bhi(p0), a1);
      a0 = fmaf(w1, blo(p1), a0); a1 = fmaf(w1, bhi(p1), a1);
      a0 = fmaf(w2, blo(p2), a0); a1 = fmaf(w2, bhi(p2), a1);
      a0 = fmaf(w3, blo(p3), a0); a1 = fmaf(w3, bhi(p3), a1);
    }
    for (; e < end; ++e){
      int s0 = clampi(g_csrc[e], 0, NN - 1);
      float w0 = g_dinv[s0];
      u32 p0 = *(const u32*)(g_hb + (size_t)s0 * 64 + cc);
      a0 = fmaf(w0, blo(p0), a0); a1 = fmaf(w0, bhi(p0), a1);
    }
    u32 ps = *(const u32*)(g_hb + (size_t)wid * 64 + cc);
    float sd = di * di;
    a0 = a0 * di + sd * blo(ps) + g_wf[boff + cc];
    a1 = a1 * di + sd * bhi(ps) + g_wf[boff + cc + 1];
    if (RELU){ a0 = fmaxf(a0, 0.f); a1 = fmaxf(a1, 0.f); }
    *(float2*)(dout + (size_t)wid * 64 + cc) = make_float2(a0, a1);  // f32 h3 (output 1)
  }
}

// ---- 6) output head: out[N x 2] = h3[N x 64] @ Wout + bout ----
__global__ __launch_bounds__(256) void k_out(const float* __restrict__ h3, float* __restrict__ out){
  __shared__ float Wl[128];
  __shared__ float bl[2];
  if (threadIdx.x < 128) Wl[threadIdx.x] = g_wf[OFF_WO + threadIdx.x];
  if (threadIdx.x < 2) bl[threadIdx.x] = g_wf[OFF_BO + threadIdx.x];
  __syncthreads();
  int i = blockIdx.x * 256 + threadIdx.x;
  if (i >= NN) return;
  const float4* hr = (const float4*)(h3 + (size_t)i * 64);
  float a0 = bl[0], a1 = bl[1];
#pragma unroll
  for (int c = 0; c < 16; ++c){
    float4 p = hr[c];
    float v[4] = {p.x, p.y, p.z, p.w};
#pragma unroll
    for (int t = 0; t < 4; ++t){
      int k = c * 4 + t;
      a0 = fmaf(v[t], Wl[k * 2 + 0], a0);
      a1 = fmaf(v[t], Wl[k * 2 + 1], a1);
    }
  }
  *(float2*)(out + (size_t)i * 2) = make_float2(a0, a1);
}

extern "C" void kernel_launch(void* const* d_in, const int* in_sizes, int n_in,
                              void* d_out, int out_size, void* d_ws, size_t ws_size,
                              hipStream_t stream){
  const int* ei = (const int*)d_in[1];
  float* out = (float*)d_out;                    // [N,2] then [N,64], f32
  float* h3  = out + (size_t)NN * 2;

  k_detect<<<1, 256, 0, stream>>>((const u16*)d_in[0], ei);
  k_cvt_x<<<2500, 256, 0, stream>>>(d_in[0]);
  k_cvt_w<<<165, 256, 0, stream>>>(d_in[2], d_in[3], d_in[4], d_in[5],
                                   d_in[6], d_in[7], d_in[8], d_in[9]);
  k_packw<<<160, 256, 0, stream>>>();
  k_zero<<<(NN + 255) / 256, 256, 0, stream>>>();
  k_count<<<(NE + 255) / 256, 256, 0, stream>>>(ei);
  k_scan1<<<40, 1024, 0, stream>>>();
  k_scan2<<<1, 64, 0, stream>>>();
  k_scan3<<<40, 1024, 0, stream>>>();
  k_fill<<<(NE + 255) / 256, 256, 0, stream>>>(ei);

  k_gemm<128><<<625, 256, 0, stream>>>(WP_W1);                           // g_ha -> g_hb
  k_agg<128, true><<<5000, 256, 0, stream>>>(OFF_B1, (float*)nullptr);   // g_hb -> g_ha (bf16)
  k_gemm<128><<<625, 256, 0, stream>>>(WP_W2);
  k_agg<128, true><<<5000, 256, 0, stream>>>(OFF_B2, (float*)nullptr);
  k_gemm<64><<<625, 256, 0, stream>>>(WP_W3);                            // g_ha -> g_hb (N x 64)
  k_agg<64, false><<<5000, 256, 0, stream>>>(OFF_B3, h3);                // g_hb -> h3 (d_out)
  k_out<<<157, 256, 0, stream>>>(h3, out);
}

// Round 11
// 275.618 us; speedup vs baseline: 2.0746x; 1.0472x over previous
//
#include <hip/hip_runtime.h>
#include <hip/hip_bf16.h>

#define NN 40000
#define NE 640000

typedef unsigned int u32;
typedef unsigned short u16;
typedef __attribute__((ext_vector_type(8))) short bf16x8;
typedef __attribute__((ext_vector_type(4))) float f32x4;

// ---------------- static device scratch (direct symbol use; no d_ws) -------
__device__ float g_wf[512];                  // biases + Wout + bout (f32)
__device__ u16   g_wp[40960];                // bf16 W1/W2/W3 in MFMA B-fragment layout
__device__ int   g_flags[4];                 // [0]=floats-are-f32, [1]=edge stride (1 or 2)
__device__ int   g_cnt[NN];
__device__ int   g_cur[NN];
__device__ int   g_rowptr[NN + 1];
__device__ float g_dinv[NN];
__device__ int   g_csrc[NE];
__device__ int   g_bsum[64];
__device__ int   g_bpre[64];
__device__ u16   g_ha[(size_t)NN * 128];     // bf16 A operand (x, then agg outputs)
__device__ u16   g_hb[(size_t)NN * 128];     // bf16 gemm output (gather operand)

// g_wf offsets
#define OFF_B1 0
#define OFF_B2 128
#define OFF_B3 256
#define OFF_WO 320
#define OFF_BO 448
// g_wp offsets
#define WP_W1 0
#define WP_W2 16384
#define WP_W3 32768

__device__ __forceinline__ float b2f(u16 v){ return __uint_as_float(((u32)v) << 16); }
__device__ __forceinline__ float blo(u32 u){ return __uint_as_float(u << 16); }
__device__ __forceinline__ float bhi(u32 u){ return __uint_as_float(u & 0xffff0000u); }
__device__ __forceinline__ u32 f2bf(float f){
  u32 u = __float_as_uint(f);
  return (u + 0x7fffu + ((u >> 16) & 1u)) >> 16;   // RNE
}
__device__ __forceinline__ int clampi(int v, int lo, int hi){ return v < lo ? lo : (v > hi ? hi : v); }
// load one element of a float-tensor input as bf16 / as f32, per detected dtype
__device__ __forceinline__ u16 ldbf(const void* p, int idx){
  return g_flags[0] ? (u16)f2bf(((const float*)p)[idx]) : ((const u16*)p)[idx];
}
__device__ __forceinline__ float ldf(const void* p, int idx){
  return g_flags[0] ? ((const float*)p)[idx] : b2f(((const u16*)p)[idx]);
}

// ---- 0) runtime dtype detection ----
__global__ __launch_bounds__(256) void k_detect(const u16* __restrict__ xf, const int* __restrict__ ei){
  __shared__ int c1, c2;
  if (threadIdx.x == 0){ c1 = 0; c2 = 0; }
  __syncthreads();
  int l1 = 0, l2 = 0;
  for (int i = threadIdx.x; i < 4096; i += 256){
    u16 v = xf[2 * i];
    int e = (v >> 7) & 0xff;
    if (v == 0 || (e >= 100 && e <= 140)) l1++;
    if (ei[2 * i + 1] == 0) l2++;
  }
  atomicAdd(&c1, l1); atomicAdd(&c2, l2);
  __syncthreads();
  if (threadIdx.x == 0){
    g_flags[0] = (c1 < 2048) ? 1 : 0;
    g_flags[1] = (c2 > 2048) ? 2 : 1;
  }
}

// ---- 0b) fused preamble: cvt_x | packw | bias table | zero counters ----
// sections: [0,640000) x->bf16 (uint4 groups); [640000,680960) packw;
//           [680960,681410) f32 table; [681410,721410) zero cnt; [721410,761450) zero cur
__global__ __launch_bounds__(256) void k_prep(const void* xin, const void* w1, const void* b1,
                                              const void* w2, const void* b2, const void* w3,
                                              const void* b3, const void* wo, const void* bo){
  int T = (int)blockIdx.x * 256 + (int)threadIdx.x;
  if (T < 640000){
    if (g_flags[0]){
      const float4* p = (const float4*)xin + (size_t)T * 2;
      float4 a = p[0], b = p[1];
      uint4 o;
      o.x = f2bf(a.x) | (f2bf(a.y) << 16);
      o.y = f2bf(a.z) | (f2bf(a.w) << 16);
      o.z = f2bf(b.x) | (f2bf(b.y) << 16);
      o.w = f2bf(b.z) | (f2bf(b.w) << 16);
      ((uint4*)g_ha)[T] = o;
    } else {
      ((uint4*)g_ha)[T] = ((const uint4*)xin)[T];
    }
  } else if (T < 680960){
    int local = T - 640000;
    int J, dstbase, l; const void* src;
    if (local < 16384){ J = 128; src = w1; dstbase = WP_W1; l = local; }
    else if (local < 32768){ J = 128; src = w2; dstbase = WP_W2; l = local - 16384; }
    else { J = 64; src = w3; dstbase = WP_W3; l = local - 32768; }
    int chunk = l >> 9, within = l & 511;
    int nbw = J / 16;
    int kb = chunk / nbw, nb = chunk % nbw;
    int lane = within >> 3, j = within & 7;
    int q = lane >> 4, n = lane & 15;
    int k = kb * 32 + q * 8 + j;
    int col = nb * 16 + n;
    g_wp[dstbase + l] = ldbf(src, k * J + col);
  } else if (T < 681410){
    int l = T - 680960;                      // 0..449
    if (l < 128)      g_wf[OFF_B1 + l] = ldf(b1, l);
    else if (l < 256) g_wf[OFF_B2 + l - 128] = ldf(b2, l - 128);
    else if (l < 320) g_wf[OFF_B3 + l - 256] = ldf(b3, l - 256);
    else if (l < 448) g_wf[OFF_WO + l - 320] = ldf(wo, l - 320);
    else              g_wf[OFF_BO + l - 448] = ldf(bo, l - 448);
  } else if (T < 721410){
    g_cnt[T - 681410] = 0;
  } else if (T < 761450){
    g_cur[T - 721410] = 0;
  }
}

// ---- 1) in-degree count, XCD-partitioned: block b counts dst in [5000*(b&7),+5000) ----
__global__ __launch_bounds__(256) void k_count(const int* __restrict__ ei){
  int part = (int)blockIdx.x & 7;
  int chunk = (int)blockIdx.x >> 3;          // 0..312
  int lo = part * 5000, hi = lo + 5000;
  int strd = g_flags[1];
  int tid = (int)threadIdx.x;
#pragma unroll
  for (int it = 0; it < 8; ++it){
    int e = chunk * 2048 + it * 256 + tid;
    if (e < NE){
      int d = clampi(ei[(size_t)(NE + e) * strd], 0, NN - 1);
      if (d >= lo && d < hi) atomicAdd(&g_cnt[d], 1);
    }
  }
}

// ---- 2a) block-level scan (40 blocks x 1024) ----
__global__ __launch_bounds__(1024) void k_scan1(){
  int t = (int)threadIdx.x;
  int b = (int)blockIdx.x;
  int i = b * 1024 + t;
  int v = (i < NN) ? g_cnt[i] : 0;
  int lane = t & 63, wv = t >> 6;
  int x = v;
#pragma unroll
  for (int ofs = 1; ofs < 64; ofs <<= 1){
    int y = __shfl_up(x, ofs, 64);
    if (lane >= ofs) x += y;
  }
  __shared__ int wsum[16];
  if (lane == 63) wsum[wv] = x;
  __syncthreads();
  if (t < 16){
    int s = wsum[t];
#pragma unroll
    for (int ofs = 1; ofs < 16; ofs <<= 1){
      int y = __shfl_up(s, ofs, 64);
      if (t >= ofs) s += y;
    }
    wsum[t] = s;
  }
  __syncthreads();
  int pre = (wv == 0) ? 0 : wsum[wv - 1];
  int incl = x + pre;
  if (i < NN){
    g_rowptr[i] = incl - v;
    g_dinv[i] = rsqrtf((float)(v + 1));
  }
  if (t == 1023) g_bsum[b] = incl;
}

// ---- 2b) scan 40 block sums ----
__global__ __launch_bounds__(64) void k_scan2(){
  int t = (int)threadIdx.x;
  int v = (t < 40) ? g_bsum[t] : 0;
  int s = v;
#pragma unroll
  for (int ofs = 1; ofs < 64; ofs <<= 1){
    int y = __shfl_up(s, ofs, 64);
    if (t >= ofs) s += y;
  }
  if (t < 40) g_bpre[t] = s - v;
  if (t == 39) g_rowptr[NN] = s;
}

// ---- 2c) add block offsets ----
__global__ __launch_bounds__(1024) void k_scan3(){
  int i = (int)blockIdx.x * 1024 + (int)threadIdx.x;
  if (i < NN) g_rowptr[i] += g_bpre[blockIdx.x];
}

// ---- 3) CSR scatter, XCD-partitioned (writes stay in one XCD's L2) ----
__global__ __launch_bounds__(256) void k_fill(const int* __restrict__ ei){
  int part = (int)blockIdx.x & 7;
  int chunk = (int)blockIdx.x >> 3;
  int lo = part * 5000, hi = lo + 5000;
  int strd = g_flags[1];
  int tid = (int)threadIdx.x;
#pragma unroll
  for (int it = 0; it < 8; ++it){
    int e = chunk * 2048 + it * 256 + tid;
    if (e < NE){
      int d = clampi(ei[(size_t)(NE + e) * strd], 0, NN - 1);
      if (d >= lo && d < hi){
        int s = clampi(ei[(size_t)e * strd], 0, NN - 1);
        int pos = clampi(g_rowptr[d] + atomicAdd(&g_cur[d], 1), 0, NE - 1);
        g_csrc[pos] = s;
      }
    }
  }
}

// ---- 4) MFMA GEMM: g_hb[N x J](bf16) = g_ha[N x 128](bf16) @ W(packed bf16) ----
template<int J>
__global__ __launch_bounds__(256) void k_gemm(int wpoff){
  constexpr int NB = J / 16;
  int tid = (int)threadIdx.x;
  int wave = tid >> 6, lane = tid & 63;
  int q = lane >> 4, n = lane & 15;
  int m0 = (int)blockIdx.x * 64 + wave * 16;
  f32x4 acc[NB];
#pragma unroll
  for (int nb = 0; nb < NB; ++nb) acc[nb] = (f32x4){0.f, 0.f, 0.f, 0.f};
  const u16* arow = g_ha + (size_t)(m0 + n) * 128 + q * 8;
#pragma unroll
  for (int kb = 0; kb < 4; ++kb){
    bf16x8 a = *(const bf16x8*)(arow + kb * 32);
    const u16* wbase = g_wp + wpoff + (kb * NB) * 512 + lane * 8;
#pragma unroll
    for (int nb = 0; nb < NB; ++nb){
      bf16x8 w = *(const bf16x8*)(wbase + nb * 512);
      acc[nb] = __builtin_amdgcn_mfma_f32_16x16x32_bf16(a, w, acc[nb], 0, 0, 0);
    }
  }
  u16* crow = g_hb + (size_t)(m0 + q * 4) * J + n;
#pragma unroll
  for (int r = 0; r < 4; ++r){
#pragma unroll
    for (int nb = 0; nb < NB; ++nb)
      crow[(size_t)r * J + nb * 16] = (u16)f2bf(acc[nb][r]);
  }
}

// ---- 5) CSR aggregation: bf16 gather, f32 acc, 8x unroll; J=64 fuses output head ----
template<int J, bool RELU>
__global__ __launch_bounds__(256) void k_agg(int boff, float* __restrict__ h3, float* __restrict__ outp){
  int wpair = (int)((blockIdx.x * 256 + threadIdx.x) >> 6);
  int lane = (int)threadIdx.x & 63;
  int sub = lane >> 5, sl = lane & 31;
  int wid = wpair * 2 + sub;
  if (wid >= NN) return;
  float di = g_dinv[wid];
  int beg = g_rowptr[wid], end = g_rowptr[wid + 1];
  if (J == 128){
    int cc = sl * 4;
    float a0 = 0.f, a1 = 0.f, a2 = 0.f, a3 = 0.f;
    int e = beg;
    for (; e + 7 < end; e += 8){
      int s[8]; uint2 p[8]; float w[8];
#pragma unroll
      for (int t = 0; t < 8; ++t) s[t] = clampi(g_csrc[e + t], 0, NN - 1);
#pragma unroll
      for (int t = 0; t < 8; ++t) p[t] = *(const uint2*)(g_hb + (size_t)s[t] * 128 + cc);
#pragma unroll
      for (int t = 0; t < 8; ++t) w[t] = g_dinv[s[t]];
#pragma unroll
      for (int t = 0; t < 8; ++t){
        a0 = fmaf(w[t], blo(p[t].x), a0); a1 = fmaf(w[t], bhi(p[t].x), a1);
        a2 = fmaf(w[t], blo(p[t].y), a2); a3 = fmaf(w[t], bhi(p[t].y), a3);
      }
    }
    for (; e < end; ++e){
      int s0 = clampi(g_csrc[e], 0, NN - 1);
      float w0 = g_dinv[s0];
      uint2 p0 = *(const uint2*)(g_hb + (size_t)s0 * 128 + cc);
      a0 = fmaf(w0, blo(p0.x), a0); a1 = fmaf(w0, bhi(p0.x), a1);
      a2 = fmaf(w0, blo(p0.y), a2); a3 = fmaf(w0, bhi(p0.y), a3);
    }
    uint2 ps = *(const uint2*)(g_hb + (size_t)wid * 128 + cc);
    float sd = di * di;
    a0 = a0 * di + sd * blo(ps.x) + g_wf[boff + cc];
    a1 = a1 * di + sd * bhi(ps.x) + g_wf[boff + cc + 1];
    a2 = a2 * di + sd * blo(ps.y) + g_wf[boff + cc + 2];
    a3 = a3 * di + sd * bhi(ps.y) + g_wf[boff + cc + 3];
    if (RELU){
      a0 = fmaxf(a0, 0.f); a1 = fmaxf(a1, 0.f);
      a2 = fmaxf(a2, 0.f); a3 = fmaxf(a3, 0.f);
    }
    uint2 o;
    o.x = f2bf(a0) | (f2bf(a1) << 16);
    o.y = f2bf(a2) | (f2bf(a3) << 16);
    *(uint2*)(g_ha + (size_t)wid * 128 + cc) = o;
  } else {
    int cc = sl * 2;
    float a0 = 0.f, a1 = 0.f;
    int e = beg;
    for (; e + 7 < end; e += 8){
      int s[8]; u32 p[8]; float w[8];
#pragma unroll
      for (int t = 0; t < 8; ++t) s[t] = clampi(g_csrc[e + t], 0, NN - 1);
#pragma unroll
      for (int t = 0; t < 8; ++t) p[t] = *(const u32*)(g_hb + (size_t)s[t] * 64 + cc);
#pragma unroll
      for (int t = 0; t < 8; ++t) w[t] = g_dinv[s[t]];
#pragma unroll
      for (int t = 0; t < 8; ++t){
        a0 = fmaf(w[t], blo(p[t]), a0); a1 = fmaf(w[t], bhi(p[t]), a1);
      }
    }
    for (; e < end; ++e){
      int s0 = clampi(g_csrc[e], 0, NN - 1);
      float w0 = g_dinv[s0];
      u32 p0 = *(const u32*)(g_hb + (size_t)s0 * 64 + cc);
      a0 = fmaf(w0, blo(p0), a0); a1 = fmaf(w0, bhi(p0), a1);
    }
    u32 ps = *(const u32*)(g_hb + (size_t)wid * 64 + cc);
    float sd = di * di;
    a0 = a0 * di + sd * blo(ps) + g_wf[boff + cc];
    a1 = a1 * di + sd * bhi(ps) + g_wf[boff + cc + 1];
    if (RELU){ a0 = fmaxf(a0, 0.f); a1 = fmaxf(a1, 0.f); }
    *(float2*)(h3 + (size_t)wid * 64 + cc) = make_float2(a0, a1);
    // fused output head: out[wid] = h3row @ Wout + bout, 32-lane shuffle reduce
    float o0 = a0 * g_wf[OFF_WO + cc * 2]     + a1 * g_wf[OFF_WO + cc * 2 + 2];
    float o1 = a0 * g_wf[OFF_WO + cc * 2 + 1] + a1 * g_wf[OFF_WO + cc * 2 + 3];
#pragma unroll
    for (int m = 1; m < 32; m <<= 1){
      o0 += __shfl_xor(o0, m, 64);
      o1 += __shfl_xor(o1, m, 64);
    }
    if (sl == 0){
      *(float2*)(outp + (size_t)wid * 2) =
        make_float2(o0 + g_wf[OFF_BO], o1 + g_wf[OFF_BO + 1]);
    }
  }
}

extern "C" void kernel_launch(void* const* d_in, const int* in_sizes, int n_in,
                              void* d_out, int out_size, void* d_ws, size_t ws_size,
                              hipStream_t stream){
  const int* ei = (const int*)d_in[1];
  float* out = (float*)d_out;                    // [N,2] then [N,64], f32
  float* h3  = out + (size_t)NN * 2;

  k_detect<<<1, 256, 0, stream>>>((const u16*)d_in[0], ei);
  k_prep<<<2975, 256, 0, stream>>>(d_in[0], d_in[2], d_in[3], d_in[4], d_in[5],
                                   d_in[6], d_in[7], d_in[8], d_in[9]);
  k_count<<<2504, 256, 0, stream>>>(ei);
  k_scan1<<<40, 1024, 0, stream>>>();
  k_scan2<<<1, 64, 0, stream>>>();
  k_scan3<<<40, 1024, 0, stream>>>();
  k_fill<<<2504, 256, 0, stream>>>(ei);

  k_gemm<128><<<625, 256, 0, stream>>>(WP_W1);                               // g_ha -> g_hb
  k_agg<128, true><<<5000, 256, 0, stream>>>(OFF_B1, (float*)nullptr, (float*)nullptr);
  k_gemm<128><<<625, 256, 0, stream>>>(WP_W2);
  k_agg<128, true><<<5000, 256, 0, stream>>>(OFF_B2, (float*)nullptr, (float*)nullptr);
  k_gemm<64><<<625, 256, 0, stream>>>(WP_W3);                                // g_ha -> g_hb (N x 64)
  k_agg<64, false><<<5000, 256, 0, stream>>>(OFF_B3, h3, out);               // + fused head
}